// Round 10
// baseline (645.915 us; speedup 1.0000x reference)
//
#include <hip/hip_runtime.h>
#include <hip/hip_bf16.h>
#include <cstdint>

// ---------------------------------------------------------------------------
// Model: 4x [LN -> QKV -> self-attn -> proj+res -> LN -> cross-attn ->
//            proj+res -> LN -> FC+GELU -> proj+res]
// B=2 T=2048 S=512 W=512 H=8 ch=64, all matmuls bf16 MFMA 16x16x32, fp32 accum.
// ---------------------------------------------------------------------------

typedef __bf16 bf16;
typedef __bf16 bf16x8 __attribute__((ext_vector_type(8)));
typedef float f32x4 __attribute__((ext_vector_type(4)));

#define AS1(p) ((__attribute__((address_space(1))) void*)(uintptr_t)(p))
#define AS3(p) ((__attribute__((address_space(3))) void*)(p))

__device__ __forceinline__ unsigned short bf2us(bf16 v) {
    return __builtin_bit_cast(unsigned short, v);
}

// counted-vmcnt barrier (GEMM pipeline): wait until <=N outstanding, barrier.
template <int N>
__device__ __forceinline__ void vmbar() {
    if constexpr (N == 0)      asm volatile("s_waitcnt vmcnt(0)\n\ts_barrier" ::: "memory");
    else if constexpr (N == 5) asm volatile("s_waitcnt vmcnt(5)\n\ts_barrier" ::: "memory");
    else if constexpr (N == 6) asm volatile("s_waitcnt vmcnt(6)\n\ts_barrier" ::: "memory");
    else if constexpr (N == 8) asm volatile("s_waitcnt vmcnt(8)\n\ts_barrier" ::: "memory");
    __builtin_amdgcn_sched_barrier(0);
}
__device__ __forceinline__ void plainbar() {
    asm volatile("s_barrier" ::: "memory");
    __builtin_amdgcn_sched_barrier(0);
}
// LDS-only barrier: waits ds ops, does NOT drain vmcnt (keeps prefetch alive)
__device__ __forceinline__ void ldsbar() {
    asm volatile("s_waitcnt lgkmcnt(0)\n\ts_barrier" ::: "memory");
    __builtin_amdgcn_sched_barrier(0);
}

// ---------------- LayerNorm (f32 in) -> bf16 out, W=512 -------------------
__global__ __launch_bounds__(256) void ln_kernel(const float* __restrict__ x,
                                                 const float* __restrict__ gam,
                                                 const float* __restrict__ bet,
                                                 bf16* __restrict__ h) {
    int row  = blockIdx.x * 4 + (threadIdx.x >> 6);
    int lane = threadIdx.x & 63;
    const float4* xr = (const float4*)(x + (size_t)row * 512) + lane * 2;
    float4 a = xr[0], b = xr[1];
    float s  = a.x + a.y + a.z + a.w + b.x + b.y + b.z + b.w;
    float ss = a.x * a.x + a.y * a.y + a.z * a.z + a.w * a.w +
               b.x * b.x + b.y * b.y + b.z * b.z + b.w * b.w;
#pragma unroll
    for (int off = 1; off < 64; off <<= 1) {
        s  += __shfl_xor(s, off);
        ss += __shfl_xor(ss, off);
    }
    float mean = s * (1.f / 512.f);
    float var  = ss * (1.f / 512.f) - mean * mean;
    float rstd = rsqrtf(fmaxf(var, 0.f) + 1e-5f);
    const float4* gr = (const float4*)gam + lane * 2;
    const float4* br = (const float4*)bet + lane * 2;
    float4 g0 = gr[0], g1 = gr[1], b0 = br[0], b1 = br[1];
    bf16x8 hv;
    hv[0] = (bf16)((a.x - mean) * rstd * g0.x + b0.x);
    hv[1] = (bf16)((a.y - mean) * rstd * g0.y + b0.y);
    hv[2] = (bf16)((a.z - mean) * rstd * g0.z + b0.z);
    hv[3] = (bf16)((a.w - mean) * rstd * g0.w + b0.w);
    hv[4] = (bf16)((b.x - mean) * rstd * g1.x + b1.x);
    hv[5] = (bf16)((b.y - mean) * rstd * g1.y + b1.y);
    hv[6] = (bf16)((b.z - mean) * rstd * g1.z + b1.z);
    hv[7] = (bf16)((b.w - mean) * rstd * g1.w + b1.w);
    *(bf16x8*)(h + (size_t)row * 512 + lane * 8) = hv;
}

// ------------- transpose+convert: in f32 [L][K][N] -> out bf16 [L][N][K] ---
__global__ void wtrans_kernel(const float* __restrict__ in, bf16* __restrict__ out,
                              int K, int N) {
    __shared__ float tile[32][33];
    int n0 = blockIdx.x * 32, k0 = blockIdx.y * 32;
    const float* ip = in + (size_t)blockIdx.z * K * N;
    bf16* op = out + (size_t)blockIdx.z * N * K;
#pragma unroll
    for (int i = threadIdx.y; i < 32; i += 8)
        tile[i][threadIdx.x] = ip[(size_t)(k0 + i) * N + n0 + threadIdx.x];
    __syncthreads();
#pragma unroll
    for (int i = threadIdx.y; i < 32; i += 8)
        op[(size_t)(n0 + i) * K + k0 + threadIdx.x] = (bf16)tile[threadIdx.x][i];
}

// ------------- elementwise f32 -> bf16 ------------------------------------
__global__ void cvt_kernel(const float* __restrict__ in, bf16* __restrict__ out, int n) {
    int i = (blockIdx.x * 256 + threadIdx.x) * 8;
    if (i + 8 <= n) {
        const float4* p = (const float4*)(in + i);
        float4 a = p[0], b = p[1];
        bf16x8 v;
        v[0] = (bf16)a.x; v[1] = (bf16)a.y; v[2] = (bf16)a.z; v[3] = (bf16)a.w;
        v[4] = (bf16)b.x; v[5] = (bf16)b.y; v[6] = (bf16)b.z; v[7] = (bf16)b.w;
        *(bf16x8*)(out + i) = v;
    }
}

// ------------- V transpose (self): qkvb V-slice -> VT[bh][64][T] bf16 ------
__global__ __launch_bounds__(256) void vtrans_self(const bf16* __restrict__ qkvb,
                                                   bf16* __restrict__ VTs, int T_) {
    __shared__ bf16 tl[64][66];
    int tb = blockIdx.x * 64;
    int bh = blockIdx.y;
    int b = bh >> 3, h = bh & 7;
    int tid = threadIdx.x;
#pragma unroll
    for (int e = 0; e < 2; ++e) {
        int idx = e * 256 + tid;         // 0..511: t x 8ch-groups
        int t = idx >> 3, ci = (idx & 7) * 8;
        bf16x8 v = *(const bf16x8*)(qkvb + ((size_t)b * T_ + tb + t) * 1536 +
                                    h * 192 + 128 + ci);
#pragma unroll
        for (int j = 0; j < 8; ++j) tl[ci + j][t] = v[j];
    }
    __syncthreads();
#pragma unroll
    for (int e = 0; e < 2; ++e) {
        int idx = e * 256 + tid;
        int ch = idx >> 3, ti = (idx & 7) * 8;
        bf16x8 v;
#pragma unroll
        for (int j = 0; j < 8; ++j) v[j] = tl[ch][ti + j];
        *(bf16x8*)(VTs + ((size_t)bh * 64 + ch) * T_ + tb + ti) = v;
    }
}

// ------------- V transpose (cross): cond_v f32 -> VT[bh][64][S] bf16 -------
__global__ __launch_bounds__(256) void vtrans_cross(const float* __restrict__ cv,
                                                    bf16* __restrict__ VTc, int S_) {
    __shared__ bf16 tl[64][66];
    int sb = blockIdx.x * 64;
    int bh = blockIdx.y;
    int b = bh >> 3, h = bh & 7;
    int tid = threadIdx.x;
#pragma unroll
    for (int e = 0; e < 4; ++e) {
        int idx = e * 256 + tid;         // 0..1023: s x 16 ch-groups(4)
        int s = idx >> 4, ci = (idx & 15) * 4;
        float4 v = *(const float4*)(cv + ((size_t)b * S_ + sb + s) * 512 + h * 64 + ci);
        tl[ci + 0][s] = (bf16)v.x; tl[ci + 1][s] = (bf16)v.y;
        tl[ci + 2][s] = (bf16)v.z; tl[ci + 3][s] = (bf16)v.w;
    }
    __syncthreads();
#pragma unroll
    for (int e = 0; e < 2; ++e) {
        int idx = e * 256 + tid;
        int ch = idx >> 3, si = (idx & 7) * 8;
        bf16x8 v;
#pragma unroll
        for (int j = 0; j < 8; ++j) v[j] = tl[ch][si + j];
        *(bf16x8*)(VTc + ((size_t)bh * 64 + ch) * S_ + sb + si) = v;
    }
}

// ------------- GEMM: C = A[M][K] @ Bt[N][K]^T + bias, BM x 128 tile --------
// Depth-2 counted-vmcnt pipeline (R9, proven).
template <int EPI, int BM>
__global__ __launch_bounds__(256) void gemm_kernel(const bf16* __restrict__ A,
                                                   const bf16* __restrict__ Bt,
                                                   const float* __restrict__ bias,
                                                   const float* res, void* out,
                                                   int M, int N, int K) {
    constexpr int MI = BM / 32;          // acc rows per wave (1/2/4)
    constexpr int LPW = BM / 32 + 4;     // vmem insts per thread per stage
    constexpr int ABYTES = BM * 128;     // bytes per A buffer
    __shared__ __align__(16) bf16 As[2 * BM * 64];
    __shared__ __align__(16) bf16 Bs[2 * 128 * 64];
    int tiles_n = N >> 7;
    int bid = blockIdx.x;
    int cpx = gridDim.x >> 3;           // grid % 8 == 0 for all our launches
    bid = (bid & 7) * cpx + (bid >> 3); // XCD-aware swizzle
    int bm = bid / tiles_n, bn = bid % tiles_n;
    int tid = threadIdx.x, wave = tid >> 6, lane = tid & 63;
    int wm = wave >> 1, wn = wave & 1;
    int g = lane >> 4, cc = lane & 15;
    f32x4 acc[MI][4] = {};
    const bf16* Ag = A + (size_t)(bm * BM) * K;
    const bf16* Bg = Bt + (size_t)(bn << 7) * K;
    int scol = (tid & 7) * 8;  // element offset within 64-wide row

    auto stage = [&](int k0, int buf) {
#pragma unroll
        for (int e = 0; e < BM / 32; ++e) {
            int row = (e * 256 + tid) >> 3;
            __builtin_amdgcn_global_load_lds(AS1(Ag + (size_t)row * K + k0 + scol),
                                             AS3((char*)As + buf * ABYTES + e * 4096 + wave * 1024),
                                             16, 0, 0);
        }
#pragma unroll
        for (int e = 0; e < 4; ++e) {
            int row = (e * 256 + tid) >> 3;
            __builtin_amdgcn_global_load_lds(AS1(Bg + (size_t)row * K + k0 + scol),
                                             AS3((char*)Bs + buf * 16384 + e * 4096 + wave * 1024),
                                             16, 0, 0);
        }
    };

    int nk = K >> 6;                     // >= 8 for all our shapes
    stage(0, 0);
    stage(64, 1);
    for (int t = 0; t < nk; ++t) {
        if (t + 1 < nk) vmbar<LPW>(); else vmbar<0>();
        const bf16* Ab = As + (t & 1) * (BM * 64);
        const bf16* Bb = Bs + (t & 1) * (128 * 64);
#pragma unroll
        for (int kk = 0; kk < 2; ++kk) {
            bf16x8 af[MI], bfr[4];
#pragma unroll
            for (int mi = 0; mi < MI; ++mi)
                af[mi] = *(const bf16x8*)(Ab + (wm * (BM / 2) + mi * 16 + cc) * 64 + kk * 32 + g * 8);
#pragma unroll
            for (int ni = 0; ni < 4; ++ni)
                bfr[ni] = *(const bf16x8*)(Bb + (wn * 64 + ni * 16 + cc) * 64 + kk * 32 + g * 8);
#pragma unroll
            for (int mi = 0; mi < MI; ++mi)
#pragma unroll
                for (int ni = 0; ni < 4; ++ni)
                    acc[mi][ni] = __builtin_amdgcn_mfma_f32_16x16x32_bf16(
                        af[mi], bfr[ni], acc[mi][ni], 0, 0, 0);
        }
        plainbar();                       // everyone done reading buf[t&1]
        if (t + 2 < nk) stage((t + 2) * 64, t & 1);
    }
    // epilogue: D[m = 4*(lane>>4)+r][n = lane&15] per 16x16 fragment
    int m0 = bm * BM + wm * (BM / 2);
    int n0 = (bn << 7) + wn * 64;
#pragma unroll
    for (int ni = 0; ni < 4; ++ni) {
        int n = n0 + ni * 16 + cc;
        float bv = bias[n];
#pragma unroll
        for (int mi = 0; mi < MI; ++mi) {
#pragma unroll
            for (int r = 0; r < 4; ++r) {
                int m = m0 + mi * 16 + g * 4 + r;
                float v = acc[mi][ni][r] + bv;
                if (EPI == 1) v = 0.5f * v * (1.f + erff(v * 0.70710678118654752f));
                if (EPI == 2)
                    ((float*)out)[(size_t)m * N + n] = res[(size_t)m * N + n] + v;
                else
                    ((bf16*)out)[(size_t)m * N + n] = (bf16)v;
            }
        }
    }
}

// ------------- flash attention v8: zero-redundancy LDS reads ---------------
// Block = 64 q, 8 waves, KVBLK=64. QK phase: wave (wq = q-half, ws = 16-s
// strip) reads its strip's kf ONCE (2 b128). P -> block-shared [64q][64s]
// swizzled buffer. lgkm-only mid barrier (prefetch stays in flight). PV
// phase re-partition: (sh = s-half, nh = ni-pair): pa 2 b128 + vf 2 b128,
// 4 MFMA. 6 b128/wave/tile total (was 9), no cross-wave read redundancy.
// No-max softmax (|s|<~1); o 2-way / l 4-way partials combined in LDS.
__global__ __launch_bounds__(512) void attn_kernel(
    const bf16* __restrict__ Qp, int q_rs, int q_hs,
    const bf16* __restrict__ Kp, int k_rs, int k_hs,
    const bf16* __restrict__ Vt, int vt_s,
    bf16* __restrict__ Op, int T_, int S_) {
    __shared__ __align__(16) char SM[40960];
    // [0,16384): K dbuf 2 x [64 s][64 ch], 128B rows, chunk^(row&7)
    // [16384,32768): V^T dbuf 2 x [64 ch][64 s], same swizzle
    // [32768,40960): P shared [64 q][64 s], 128B rows, chunk^(row&7)

    int numQ = T_ >> 6;
    int phys = blockIdx.x;
    int cpx = gridDim.x >> 3;              // grid % 8 == 0
    int bid = (phys & 7) * cpx + (phys >> 3);
    int qb = bid % numQ;
    int bh = bid / numQ;
    int b = bh >> 3, h = bh & 7;
    int tid = threadIdx.x, wave = tid >> 6, lane = tid & 63;
    int wq = wave >> 2, ws = wave & 3;     // q-half, s-strip
    int sh = ws >> 1, nh = ws & 1;         // PV roles: s-half, ni-pair
    int g = lane >> 4, cc = lane & 15;
    int qrow0 = qb * 64;

    const bf16* Qb = Qp + ((size_t)b * T_ + qrow0 + wq * 32) * q_rs + h * q_hs;
    const bf16* Kb = Kp + ((size_t)b * S_) * k_rs + h * k_hs;
    const bf16* Vtb = Vt + (size_t)bh * 64 * vt_s;
    char* PB = SM + 32768;

    // Q fragments: lane holds Q[q=wq*32+qn*16+cc][k=kk*32+8g+j], pre-scaled
    // by (1/sqrt(ch))*log2(e) so softmax is exp2() directly.
    const float QSC = 0.125f * 1.44269504088896f;
    bf16x8 qf[2][2];
#pragma unroll
    for (int qn = 0; qn < 2; ++qn)
#pragma unroll
        for (int kk = 0; kk < 2; ++kk) {
            bf16x8 raw = *(const bf16x8*)(Qb + (size_t)(qn * 16 + cc) * q_rs + kk * 32 + g * 8);
            bf16x8 sc;
#pragma unroll
            for (int j = 0; j < 8; ++j) sc[j] = (bf16)((float)raw[j] * QSC);
            qf[qn][kk] = sc;
        }

    float l_acc[2] = {0.f, 0.f};
    f32x4 o_acc[2][2] = {};

    auto stage = [&](int s0, int buf) {
        // one 16B load per thread for K, one for V^T; source pre-swizzled.
        int row = tid >> 3, cp = tid & 7;
        int col = (cp ^ (row & 7)) * 8;
        __builtin_amdgcn_global_load_lds(AS1(Kb + (size_t)(s0 + row) * k_rs + col),
                                         AS3(SM + buf * 8192 + wave * 1024), 16, 0, 0);
        __builtin_amdgcn_global_load_lds(AS1(Vtb + (size_t)row * vt_s + s0 + col),
                                         AS3(SM + 16384 + buf * 8192 + wave * 1024), 16, 0, 0);
    };

    stage(0, 0);
    __syncthreads();

    int nt = S_ >> 6;
    int cur = 0;
    for (int t = 0; t < nt; ++t) {
        if (t + 1 < nt) stage((t + 1) * 64, cur ^ 1);
        char* kbc = SM + cur * 8192;
        char* vbc = SM + 16384 + cur * 8192;
        // ---- QK^T (swapped): sf[qn][r] = S^T[s=ws*16+4g+r][q=wq*32+qn*16+cc]
        f32x4 sf[2] = {};
        __builtin_amdgcn_s_setprio(1);
#pragma unroll
        for (int kk = 0; kk < 2; ++kk) {
            int krow = ws * 16 + cc;
            bf16x8 kf = *(const bf16x8*)(kbc + krow * 128 + (((kk * 4 + g) ^ (krow & 7)) << 4));
#pragma unroll
            for (int qn = 0; qn < 2; ++qn)
                sf[qn] = __builtin_amdgcn_mfma_f32_16x16x32_bf16(kf, qf[qn][kk], sf[qn], 0, 0, 0);
        }
        __builtin_amdgcn_s_setprio(0);
        // ---- no-max softmax; write P to shared [64q][64s] swizzled buffer
#pragma unroll
        for (int qn = 0; qn < 2; ++qn) {
            float p0 = exp2f(sf[qn][0]), p1 = exp2f(sf[qn][1]);
            float p2 = exp2f(sf[qn][2]), p3 = exp2f(sf[qn][3]);
            l_acc[qn] += (p0 + p1) + (p2 + p3);
            uint32_t u01 = (uint32_t)bf2us((bf16)p0) | ((uint32_t)bf2us((bf16)p1) << 16);
            uint32_t u23 = (uint32_t)bf2us((bf16)p2) | ((uint32_t)bf2us((bf16)p3) << 16);
            int prow = wq * 32 + qn * 16 + cc;
            int chunk = ws * 2 + (g >> 1);         // = (ws*16+4g)>>3
            char* pb = PB + prow * 128 + ((chunk ^ (prow & 7)) << 4) + (g & 1) * 8;
            uint2 uu; uu.x = u01; uu.y = u23;
            *(uint2*)pb = uu;
        }
        ldsbar();   // P visible to all waves; vmcnt prefetch NOT drained
        // ---- PV: o[q][ch] += P[q][s] V^T[ch][s] over s-half sh, ni-pair nh
        __builtin_amdgcn_s_setprio(1);
        bf16x8 pa[2], vf[2];
#pragma unroll
        for (int qn = 0; qn < 2; ++qn) {
            int prow = wq * 32 + qn * 16 + cc;
            pa[qn] = *(const bf16x8*)(PB + prow * 128 + (((sh * 4 + g) ^ (prow & 7)) << 4));
        }
#pragma unroll
        for (int nj = 0; nj < 2; ++nj) {
            int vrow = (nh * 2 + nj) * 16 + cc;
            vf[nj] = *(const bf16x8*)(vbc + vrow * 128 + (((sh * 4 + g) ^ (vrow & 7)) << 4));
        }
#pragma unroll
        for (int qn = 0; qn < 2; ++qn)
#pragma unroll
            for (int nj = 0; nj < 2; ++nj)
                o_acc[qn][nj] = __builtin_amdgcn_mfma_f32_16x16x32_bf16(
                    pa[qn], vf[nj], o_acc[qn][nj], 0, 0, 0);
        __builtin_amdgcn_s_setprio(0);
        __syncthreads();  // release K/V/P[cur]; drains stage(t+1)
        cur ^= 1;
    }

    // ---- combine partials: o over sh (2-way), l over ws (4-way) ----
#pragma unroll
    for (int qn = 0; qn < 2; ++qn) {
        l_acc[qn] += __shfl_xor(l_acc[qn], 16);
        l_acc[qn] += __shfl_xor(l_acc[qn], 32);
    }
    float* sco = (float*)SM;           // 8 waves x [32 q][32 ch] f32 = 32KB
    float* lf  = (float*)(SM + 32768); // 8 waves x 32 q
    float* scw = sco + wave * 1024;
#pragma unroll
    for (int qn = 0; qn < 2; ++qn) {
        if (g == 0) lf[wave * 32 + qn * 16 + cc] = l_acc[qn];
#pragma unroll
        for (int nj = 0; nj < 2; ++nj)
#pragma unroll
            for (int r = 0; r < 4; ++r)
                scw[(qn * 16 + 4 * g + r) * 32 + nj * 16 + cc] = o_acc[qn][nj][r];
    }
    __syncthreads();
    int q = tid >> 3, c0 = (tid & 7) * 8;   // q 0..63, ch base 0..56
    int wqq = q >> 5, qr = q & 31;
    int nhh = c0 >> 5, chl = c0 & 31;
    float l = lf[(wqq * 4 + 0) * 32 + qr] + lf[(wqq * 4 + 1) * 32 + qr] +
              lf[(wqq * 4 + 2) * 32 + qr] + lf[(wqq * 4 + 3) * 32 + qr];
    float inv = 1.f / l;
    const float* p0p = sco + (wqq * 4 + 0 * 2 + nhh) * 1024 + qr * 32 + chl;
    const float* p1p = sco + (wqq * 4 + 1 * 2 + nhh) * 1024 + qr * 32 + chl;
    bf16x8 o1;
#pragma unroll
    for (int e = 0; e < 2; ++e) {
        float4 v0 = *(const float4*)(p0p + e * 4);
        float4 v1 = *(const float4*)(p1p + e * 4);
        o1[e * 4 + 0] = (bf16)((v0.x + v1.x) * inv);
        o1[e * 4 + 1] = (bf16)((v0.y + v1.y) * inv);
        o1[e * 4 + 2] = (bf16)((v0.z + v1.z) * inv);
        o1[e * 4 + 3] = (bf16)((v0.w + v1.w) * inv);
    }
    *(bf16x8*)(Op + ((size_t)b * T_ + qrow0 + q) * 512 + h * 64 + c0) = o1;
}

// ---------------------------------------------------------------------------
extern "C" void kernel_launch(void* const* d_in, const int* in_sizes, int n_in,
                              void* d_out, int out_size, void* d_ws, size_t ws_size,
                              hipStream_t stream) {
    const float* x_in    = (const float*)d_in[0];
    const float* cond_k  = (const float*)d_in[1];
    const float* cond_v  = (const float*)d_in[2];
    const float* qkv_w   = (const float*)d_in[3];
    const float* qkv_b   = (const float*)d_in[4];
    const float* attn_w  = (const float*)d_in[5];
    const float* attn_b  = (const float*)d_in[6];
    const float* cross_w = (const float*)d_in[7];
    const float* cross_b = (const float*)d_in[8];
    const float* fc_w    = (const float*)d_in[9];
    const float* fc_b    = (const float*)d_in[10];
    const float* mlp_w   = (const float*)d_in[11];
    const float* mlp_b   = (const float*)d_in[12];
    const float* ln1_g   = (const float*)d_in[13];
    const float* ln1_b   = (const float*)d_in[14];
    const float* ln3_g   = (const float*)d_in[15];
    const float* ln3_b   = (const float*)d_in[16];
    const float* ln4_g   = (const float*)d_in[17];
    const float* ln4_b   = (const float*)d_in[18];

    const int L = 4, T = 2048, S = 512, W = 512;
    const int M = 2 * T;  // B*T rows

    char* ws = (char*)d_ws;
    size_t off = 0;
    auto carve = [&](size_t bytes) -> char* {
        char* p = ws + off;
        off += (bytes + 255) & ~(size_t)255;
        return p;
    };
    bf16* wqkv  = (bf16*)carve((size_t)L * 1536 * 512 * 2);
    bf16* wattn = (bf16*)carve((size_t)L * 512 * 512 * 2);
    bf16* wcrs  = (bf16*)carve((size_t)L * 512 * 512 * 2);
    bf16* wfc   = (bf16*)carve((size_t)L * 2048 * 512 * 2);
    bf16* wmlp  = (bf16*)carve((size_t)L * 512 * 2048 * 2);
    bf16* ckb   = (bf16*)carve((size_t)2 * S * W * 2);
    bf16* VTs   = (bf16*)carve((size_t)16 * 64 * T * 2);   // self V^T per layer
    bf16* VTc   = (bf16*)carve((size_t)16 * 64 * S * 2);   // cross V^T (once)
    bf16* hbuf  = (bf16*)carve((size_t)M * 512 * 2);
    bf16* qkvb  = (bf16*)carve((size_t)M * 1536 * 2);
    bf16* abuf  = (bf16*)carve((size_t)M * 512 * 2);
    bf16* fcb   = (bf16*)carve((size_t)M * 2048 * 2);

    dim3 tb(32, 8);
    wtrans_kernel<<<dim3(1536 / 32, 512 / 32, L), tb, 0, stream>>>(qkv_w, wqkv, 512, 1536);
    wtrans_kernel<<<dim3(512 / 32, 512 / 32, L), tb, 0, stream>>>(attn_w, wattn, 512, 512);
    wtrans_kernel<<<dim3(512 / 32, 512 / 32, L), tb, 0, stream>>>(cross_w, wcrs, 512, 512);
    wtrans_kernel<<<dim3(2048 / 32, 512 / 32, L), tb, 0, stream>>>(fc_w, wfc, 512, 2048);
    wtrans_kernel<<<dim3(512 / 32, 2048 / 32, L), tb, 0, stream>>>(mlp_w, wmlp, 2048, 512);
    cvt_kernel<<<(2 * S * W) / 2048, 256, 0, stream>>>(cond_k, ckb, 2 * S * W);
    vtrans_cross<<<dim3(S / 64, 16), 256, 0, stream>>>(cond_v, VTc, S);

    float* x = (float*)d_out;
    hipMemcpyAsync(x, (const void*)x_in, (size_t)M * W * sizeof(float),
                   hipMemcpyDeviceToDevice, stream);

    const int nAttn = 16 * (T / 64);        // 512 blocks
    for (int i = 0; i < L; ++i) {
        // ---- self-attention sub-block ----
        ln_kernel<<<M / 4, 256, 0, stream>>>(x, ln1_g + i * 512, ln1_b + i * 512, hbuf);
        gemm_kernel<0, 64><<<(M / 64) * (1536 / 128), 256, 0, stream>>>(
            hbuf, wqkv + (size_t)i * 1536 * 512, qkv_b + i * 1536, nullptr, qkvb,
            M, 1536, 512);
        vtrans_self<<<dim3(T / 64, 16), 256, 0, stream>>>(qkvb, VTs, T);
        attn_kernel<<<nAttn, 512, 0, stream>>>(
            qkvb, 1536, 192, qkvb + 64, 1536, 192, VTs, T,
            abuf, T, T);
        gemm_kernel<2, 32><<<(M / 32) * (512 / 128), 256, 0, stream>>>(
            abuf, wattn + (size_t)i * 512 * 512, attn_b + i * 512, x, x,
            M, 512, 512);
        // ---- cross-attention sub-block ----
        ln_kernel<<<M / 4, 256, 0, stream>>>(x, ln3_g + i * 512, ln3_b + i * 512, hbuf);
        attn_kernel<<<nAttn, 512, 0, stream>>>(
            hbuf, 512, 64, ckb, 512, 64, VTc, S,
            abuf, T, S);
        gemm_kernel<2, 32><<<(M / 32) * (512 / 128), 256, 0, stream>>>(
            abuf, wcrs + (size_t)i * 512 * 512, cross_b + i * 512, x, x,
            M, 512, 512);
        // ---- MLP sub-block ----
        ln_kernel<<<M / 4, 256, 0, stream>>>(x, ln4_g + i * 512, ln4_b + i * 512, hbuf);
        gemm_kernel<1, 128><<<(M / 128) * (2048 / 128), 256, 0, stream>>>(
            hbuf, wfc + (size_t)i * 2048 * 512, fc_b + i * 2048, nullptr, fcb,
            M, 2048, 512);
        gemm_kernel<2, 32><<<(M / 32) * (512 / 128), 256, 0, stream>>>(
            fcb, wmlp + (size_t)i * 512 * 2048, mlp_b + i * 512, x, x,
            M, 512, 2048);
    }
}

// Round 11
// 638.540 us; speedup vs baseline: 1.0115x; 1.0115x over previous
//
#include <hip/hip_runtime.h>
#include <hip/hip_bf16.h>
#include <cstdint>

// ---------------------------------------------------------------------------
// Model: 4x [LN -> QKV -> self-attn -> proj+res -> LN -> cross-attn ->
//            proj+res -> LN -> FC+GELU -> proj+res]
// B=2 T=2048 S=512 W=512 H=8 ch=64, all matmuls bf16 MFMA 16x16x32, fp32 accum.
// ---------------------------------------------------------------------------

typedef __bf16 bf16;
typedef __bf16 bf16x8 __attribute__((ext_vector_type(8)));
typedef float f32x4 __attribute__((ext_vector_type(4)));

#define AS1(p) ((__attribute__((address_space(1))) void*)(uintptr_t)(p))
#define AS3(p) ((__attribute__((address_space(3))) void*)(p))

__device__ __forceinline__ unsigned short bf2us(bf16 v) {
    return __builtin_bit_cast(unsigned short, v);
}

// counted-vmcnt barrier (GEMM pipeline): wait until <=N outstanding, barrier.
template <int N>
__device__ __forceinline__ void vmbar() {
    if constexpr (N == 0)      asm volatile("s_waitcnt vmcnt(0)\n\ts_barrier" ::: "memory");
    else if constexpr (N == 5) asm volatile("s_waitcnt vmcnt(5)\n\ts_barrier" ::: "memory");
    else if constexpr (N == 6) asm volatile("s_waitcnt vmcnt(6)\n\ts_barrier" ::: "memory");
    else if constexpr (N == 8) asm volatile("s_waitcnt vmcnt(8)\n\ts_barrier" ::: "memory");
    __builtin_amdgcn_sched_barrier(0);
}
__device__ __forceinline__ void plainbar() {
    asm volatile("s_barrier" ::: "memory");
    __builtin_amdgcn_sched_barrier(0);
}

// ---------------- LayerNorm (f32 in) -> bf16 out, W=512 -------------------
__global__ __launch_bounds__(256) void ln_kernel(const float* __restrict__ x,
                                                 const float* __restrict__ gam,
                                                 const float* __restrict__ bet,
                                                 bf16* __restrict__ h) {
    int row  = blockIdx.x * 4 + (threadIdx.x >> 6);
    int lane = threadIdx.x & 63;
    const float4* xr = (const float4*)(x + (size_t)row * 512) + lane * 2;
    float4 a = xr[0], b = xr[1];
    float s  = a.x + a.y + a.z + a.w + b.x + b.y + b.z + b.w;
    float ss = a.x * a.x + a.y * a.y + a.z * a.z + a.w * a.w +
               b.x * b.x + b.y * b.y + b.z * b.z + b.w * b.w;
#pragma unroll
    for (int off = 1; off < 64; off <<= 1) {
        s  += __shfl_xor(s, off);
        ss += __shfl_xor(ss, off);
    }
    float mean = s * (1.f / 512.f);
    float var  = ss * (1.f / 512.f) - mean * mean;
    float rstd = rsqrtf(fmaxf(var, 0.f) + 1e-5f);
    const float4* gr = (const float4*)gam + lane * 2;
    const float4* br = (const float4*)bet + lane * 2;
    float4 g0 = gr[0], g1 = gr[1], b0 = br[0], b1 = br[1];
    bf16x8 hv;
    hv[0] = (bf16)((a.x - mean) * rstd * g0.x + b0.x);
    hv[1] = (bf16)((a.y - mean) * rstd * g0.y + b0.y);
    hv[2] = (bf16)((a.z - mean) * rstd * g0.z + b0.z);
    hv[3] = (bf16)((a.w - mean) * rstd * g0.w + b0.w);
    hv[4] = (bf16)((b.x - mean) * rstd * g1.x + b1.x);
    hv[5] = (bf16)((b.y - mean) * rstd * g1.y + b1.y);
    hv[6] = (bf16)((b.z - mean) * rstd * g1.z + b1.z);
    hv[7] = (bf16)((b.w - mean) * rstd * g1.w + b1.w);
    *(bf16x8*)(h + (size_t)row * 512 + lane * 8) = hv;
}

// ------------- transpose+convert: in f32 [L][K][N] -> out bf16 [L][N][K] ---
__global__ void wtrans_kernel(const float* __restrict__ in, bf16* __restrict__ out,
                              int K, int N) {
    __shared__ float tile[32][33];
    int n0 = blockIdx.x * 32, k0 = blockIdx.y * 32;
    const float* ip = in + (size_t)blockIdx.z * K * N;
    bf16* op = out + (size_t)blockIdx.z * N * K;
#pragma unroll
    for (int i = threadIdx.y; i < 32; i += 8)
        tile[i][threadIdx.x] = ip[(size_t)(k0 + i) * N + n0 + threadIdx.x];
    __syncthreads();
#pragma unroll
    for (int i = threadIdx.y; i < 32; i += 8)
        op[(size_t)(n0 + i) * K + k0 + threadIdx.x] = (bf16)tile[threadIdx.x][i];
}

// ------------- elementwise f32 -> bf16 ------------------------------------
__global__ void cvt_kernel(const float* __restrict__ in, bf16* __restrict__ out, int n) {
    int i = (blockIdx.x * 256 + threadIdx.x) * 8;
    if (i + 8 <= n) {
        const float4* p = (const float4*)(in + i);
        float4 a = p[0], b = p[1];
        bf16x8 v;
        v[0] = (bf16)a.x; v[1] = (bf16)a.y; v[2] = (bf16)a.z; v[3] = (bf16)a.w;
        v[4] = (bf16)b.x; v[5] = (bf16)b.y; v[6] = (bf16)b.z; v[7] = (bf16)b.w;
        *(bf16x8*)(out + i) = v;
    }
}

// ------------- V transpose (self): qkvb V-slice -> VT[bh][64][T] bf16 ------
__global__ __launch_bounds__(256) void vtrans_self(const bf16* __restrict__ qkvb,
                                                   bf16* __restrict__ VTs, int T_) {
    __shared__ bf16 tl[64][66];
    int tb = blockIdx.x * 64;
    int bh = blockIdx.y;
    int b = bh >> 3, h = bh & 7;
    int tid = threadIdx.x;
#pragma unroll
    for (int e = 0; e < 2; ++e) {
        int idx = e * 256 + tid;         // 0..511: t x 8ch-groups
        int t = idx >> 3, ci = (idx & 7) * 8;
        bf16x8 v = *(const bf16x8*)(qkvb + ((size_t)b * T_ + tb + t) * 1536 +
                                    h * 192 + 128 + ci);
#pragma unroll
        for (int j = 0; j < 8; ++j) tl[ci + j][t] = v[j];
    }
    __syncthreads();
#pragma unroll
    for (int e = 0; e < 2; ++e) {
        int idx = e * 256 + tid;
        int ch = idx >> 3, ti = (idx & 7) * 8;
        bf16x8 v;
#pragma unroll
        for (int j = 0; j < 8; ++j) v[j] = tl[ch][ti + j];
        *(bf16x8*)(VTs + ((size_t)bh * 64 + ch) * T_ + tb + ti) = v;
    }
}

// ------------- V transpose (cross): cond_v f32 -> VT[bh][64][S] bf16 -------
__global__ __launch_bounds__(256) void vtrans_cross(const float* __restrict__ cv,
                                                    bf16* __restrict__ VTc, int S_) {
    __shared__ bf16 tl[64][66];
    int sb = blockIdx.x * 64;
    int bh = blockIdx.y;
    int b = bh >> 3, h = bh & 7;
    int tid = threadIdx.x;
#pragma unroll
    for (int e = 0; e < 4; ++e) {
        int idx = e * 256 + tid;         // 0..1023: s x 16 ch-groups(4)
        int s = idx >> 4, ci = (idx & 15) * 4;
        float4 v = *(const float4*)(cv + ((size_t)b * S_ + sb + s) * 512 + h * 64 + ci);
        tl[ci + 0][s] = (bf16)v.x; tl[ci + 1][s] = (bf16)v.y;
        tl[ci + 2][s] = (bf16)v.z; tl[ci + 3][s] = (bf16)v.w;
    }
    __syncthreads();
#pragma unroll
    for (int e = 0; e < 2; ++e) {
        int idx = e * 256 + tid;
        int ch = idx >> 3, si = (idx & 7) * 8;
        bf16x8 v;
#pragma unroll
        for (int j = 0; j < 8; ++j) v[j] = tl[ch][si + j];
        *(bf16x8*)(VTc + ((size_t)bh * 64 + ch) * S_ + sb + si) = v;
    }
}

// ------------- GEMM: C = A[M][K] @ Bt[N][K]^T + bias, BM x 128 tile --------
// Depth-2 counted-vmcnt pipeline (R9, proven).
template <int EPI, int BM>
__global__ __launch_bounds__(256) void gemm_kernel(const bf16* __restrict__ A,
                                                   const bf16* __restrict__ Bt,
                                                   const float* __restrict__ bias,
                                                   const float* res, void* out,
                                                   int M, int N, int K) {
    constexpr int MI = BM / 32;          // acc rows per wave (1/2/4)
    constexpr int LPW = BM / 32 + 4;     // vmem insts per thread per stage
    constexpr int ABYTES = BM * 128;     // bytes per A buffer
    __shared__ __align__(16) bf16 As[2 * BM * 64];
    __shared__ __align__(16) bf16 Bs[2 * 128 * 64];
    int tiles_n = N >> 7;
    int bid = blockIdx.x;
    int cpx = gridDim.x >> 3;           // grid % 8 == 0 for all our launches
    bid = (bid & 7) * cpx + (bid >> 3); // XCD-aware swizzle
    int bm = bid / tiles_n, bn = bid % tiles_n;
    int tid = threadIdx.x, wave = tid >> 6, lane = tid & 63;
    int wm = wave >> 1, wn = wave & 1;
    int g = lane >> 4, cc = lane & 15;
    f32x4 acc[MI][4] = {};
    const bf16* Ag = A + (size_t)(bm * BM) * K;
    const bf16* Bg = Bt + (size_t)(bn << 7) * K;
    int scol = (tid & 7) * 8;  // element offset within 64-wide row

    auto stage = [&](int k0, int buf) {
#pragma unroll
        for (int e = 0; e < BM / 32; ++e) {
            int row = (e * 256 + tid) >> 3;
            __builtin_amdgcn_global_load_lds(AS1(Ag + (size_t)row * K + k0 + scol),
                                             AS3((char*)As + buf * ABYTES + e * 4096 + wave * 1024),
                                             16, 0, 0);
        }
#pragma unroll
        for (int e = 0; e < 4; ++e) {
            int row = (e * 256 + tid) >> 3;
            __builtin_amdgcn_global_load_lds(AS1(Bg + (size_t)row * K + k0 + scol),
                                             AS3((char*)Bs + buf * 16384 + e * 4096 + wave * 1024),
                                             16, 0, 0);
        }
    };

    int nk = K >> 6;                     // >= 8 for all our shapes
    stage(0, 0);
    stage(64, 1);
    for (int t = 0; t < nk; ++t) {
        if (t + 1 < nk) vmbar<LPW>(); else vmbar<0>();
        const bf16* Ab = As + (t & 1) * (BM * 64);
        const bf16* Bb = Bs + (t & 1) * (128 * 64);
#pragma unroll
        for (int kk = 0; kk < 2; ++kk) {
            bf16x8 af[MI], bfr[4];
#pragma unroll
            for (int mi = 0; mi < MI; ++mi)
                af[mi] = *(const bf16x8*)(Ab + (wm * (BM / 2) + mi * 16 + cc) * 64 + kk * 32 + g * 8);
#pragma unroll
            for (int ni = 0; ni < 4; ++ni)
                bfr[ni] = *(const bf16x8*)(Bb + (wn * 64 + ni * 16 + cc) * 64 + kk * 32 + g * 8);
#pragma unroll
            for (int mi = 0; mi < MI; ++mi)
#pragma unroll
                for (int ni = 0; ni < 4; ++ni)
                    acc[mi][ni] = __builtin_amdgcn_mfma_f32_16x16x32_bf16(
                        af[mi], bfr[ni], acc[mi][ni], 0, 0, 0);
        }
        plainbar();                       // everyone done reading buf[t&1]
        if (t + 2 < nk) stage((t + 2) * 64, t & 1);
    }
    // epilogue: D[m = 4*(lane>>4)+r][n = lane&15] per 16x16 fragment
    int m0 = bm * BM + wm * (BM / 2);
    int n0 = (bn << 7) + wn * 64;
#pragma unroll
    for (int ni = 0; ni < 4; ++ni) {
        int n = n0 + ni * 16 + cc;
        float bv = bias[n];
#pragma unroll
        for (int mi = 0; mi < MI; ++mi) {
#pragma unroll
            for (int r = 0; r < 4; ++r) {
                int m = m0 + mi * 16 + g * 4 + r;
                float v = acc[mi][ni][r] + bv;
                if (EPI == 1) v = 0.5f * v * (1.f + erff(v * 0.70710678118654752f));
                if (EPI == 2)
                    ((float*)out)[(size_t)m * N + n] = res[(size_t)m * N + n] + v;
                else
                    ((bf16*)out)[(size_t)m * N + n] = (bf16)v;
            }
        }
    }
}

// ------------- flash attention v9: R7 schedule, KVBLK=128 ------------------
// Block = 64 q, 8 waves, KVBLK=128 -> ONE barrier per 128 of S (half of R7).
// Wave (wq,ws): q-rows wq*16..+15, s-half ws (64 s) of the tile. Swapped
// QK^T, no-max softmax (|s|<~1): per-lane scalar denominator. Private
// per-wave P [16q][64s]. LDS 80KB -> 2 blocks/CU = 16 waves/CU.
// o/l s-half partials combined once in LDS at kernel end.
__global__ __launch_bounds__(512) void attn_kernel(
    const bf16* __restrict__ Qp, int q_rs, int q_hs,
    const bf16* __restrict__ Kp, int k_rs, int k_hs,
    const bf16* __restrict__ Vt, int vt_s,
    bf16* __restrict__ Op, int T_, int S_) {
    __shared__ __align__(16) char SM[81920];
    // [0,32768): K dbuf 2 x [128 s][64 ch], 128B rows, chunk^(row&7)
    // [32768,65536): V^T dbuf 2 x [64 ch][128 s], 256B rows, chunk^(row&15)
    // [65536,81920): P, 8 waves x 2KB ([16 q][64 s], 128B rows, chunk^(cc&7))

    int numQ = T_ >> 6;
    int phys = blockIdx.x;
    int cpx = gridDim.x >> 3;              // grid % 8 == 0
    int bid = (phys & 7) * cpx + (phys >> 3);
    int qb = bid % numQ;
    int bh = bid / numQ;
    int b = bh >> 3, h = bh & 7;
    int tid = threadIdx.x, wave = tid >> 6, lane = tid & 63;
    int wq = wave >> 1, ws = wave & 1;     // q-block, s-half
    int g = lane >> 4, cc = lane & 15;
    int qrow0 = qb * 64;
    int swz = cc & 7;

    const bf16* Qb = Qp + ((size_t)b * T_ + qrow0 + wq * 16) * q_rs + h * q_hs;
    const bf16* Kb = Kp + ((size_t)b * S_) * k_rs + h * k_hs;
    const bf16* Vtb = Vt + (size_t)bh * 64 * vt_s;

    // Q fragments (B-operand): lane holds Q[q=wq*16+cc][k=kk*32+8g+j],
    // pre-scaled by (1/sqrt(ch))*log2(e) so softmax is exp2() directly.
    const float QSC = 0.125f * 1.44269504088896f;
    bf16x8 qf[2];
#pragma unroll
    for (int kk = 0; kk < 2; ++kk) {
        bf16x8 raw = *(const bf16x8*)(Qb + (size_t)cc * q_rs + kk * 32 + g * 8);
        bf16x8 sc;
#pragma unroll
        for (int j = 0; j < 8; ++j) sc[j] = (bf16)((float)raw[j] * QSC);
        qf[kk] = sc;
    }

    float l_acc = 0.f;
    f32x4 o_acc[4] = {};
    char* Pw = SM + 65536 + wave * 2048;

    auto stage = [&](int s0, int buf) {
        // K tile 128x64: 2 x 16B per thread; source pre-swizzled.
#pragma unroll
        for (int e = 0; e < 2; ++e) {
            int L = e * 512 + tid;
            int row = L >> 3, cp = L & 7;
            int col = (cp ^ (row & 7)) * 8;
            __builtin_amdgcn_global_load_lds(AS1(Kb + (size_t)(s0 + row) * k_rs + col),
                                             AS3(SM + buf * 16384 + e * 8192 + wave * 1024), 16, 0, 0);
        }
        // V^T tile 64x128 (256B rows): 2 x 16B per thread; source pre-swizzled.
#pragma unroll
        for (int e = 0; e < 2; ++e) {
            int L = e * 512 + tid;
            int row = L >> 4, cp = L & 15;
            int scl = (cp ^ (row & 15)) * 8;
            __builtin_amdgcn_global_load_lds(AS1(Vtb + (size_t)row * vt_s + s0 + scl),
                                             AS3(SM + 32768 + buf * 16384 + e * 8192 + wave * 1024), 16, 0, 0);
        }
    };

    stage(0, 0);
    __syncthreads();

    int nt = S_ >> 7;
    int cur = 0;
    for (int t = 0; t < nt; ++t) {
        if (t + 1 < nt) stage((t + 1) * 128, cur ^ 1);
        char* kbc = SM + cur * 16384;
        char* vbc = SM + 32768 + cur * 16384;
        // QK^T (swapped): sf[sn][r] = S^T[s=ws*64+sn*16+4g+r][q=wq*16+cc]
        f32x4 sf[4] = {};
        __builtin_amdgcn_s_setprio(1);
#pragma unroll
        for (int kk = 0; kk < 2; ++kk)
#pragma unroll
            for (int sn = 0; sn < 4; ++sn) {
                int row = ws * 64 + sn * 16 + cc;
                bf16x8 kf = *(const bf16x8*)(kbc + row * 128 + (((kk * 4 + g) ^ (row & 7)) << 4));
                sf[sn] = __builtin_amdgcn_mfma_f32_16x16x32_bf16(kf, qf[kk], sf[sn], 0, 0, 0);
            }
        __builtin_amdgcn_s_setprio(0);
        // no-max softmax: p = exp2(s); per-lane scalar partial denominator
#pragma unroll
        for (int sn = 0; sn < 4; ++sn) {
            float p0 = exp2f(sf[sn][0]), p1 = exp2f(sf[sn][1]);
            float p2 = exp2f(sf[sn][2]), p3 = exp2f(sf[sn][3]);
            l_acc += (p0 + p1) + (p2 + p3);
            uint32_t u01 = (uint32_t)bf2us((bf16)p0) | ((uint32_t)bf2us((bf16)p1) << 16);
            uint32_t u23 = (uint32_t)bf2us((bf16)p2) | ((uint32_t)bf2us((bf16)p3) << 16);
            // P[q=cc][s_local=sn*16+4g+r]: chunk = sn*2+(g>>1), ^swz
            char* pb = Pw + cc * 128 + (((sn * 2 + (g >> 1)) ^ swz) << 4) + (g & 1) * 8;
            uint2 uu; uu.x = u01; uu.y = u23;
            *(uint2*)pb = uu;
        }
        // PV over the wave's 64-s half: o[q][ch] += P[q][s] * V^T[ch][s]
        __builtin_amdgcn_s_setprio(1);
#pragma unroll
        for (int kk = 0; kk < 2; ++kk) {
            bf16x8 pa = *(const bf16x8*)(Pw + cc * 128 + (((kk * 4 + g) ^ swz) << 4));
#pragma unroll
            for (int ni = 0; ni < 4; ++ni) {
                int vrow = ni * 16 + cc;
                bf16x8 vf = *(const bf16x8*)(vbc + vrow * 256 +
                                             (((ws * 8 + kk * 4 + g) ^ (vrow & 15)) << 4));
                o_acc[ni] = __builtin_amdgcn_mfma_f32_16x16x32_bf16(pa, vf, o_acc[ni], 0, 0, 0);
            }
        }
        __builtin_amdgcn_s_setprio(0);
        __syncthreads();  // ONE barrier per 128-tile: release bufs + drain stage
        cur ^= 1;
    }

    // ---- cross-half combine (ws partials -> full), in LDS ----
    l_acc += __shfl_xor(l_acc, 16);
    l_acc += __shfl_xor(l_acc, 32);   // lane (g,cc): full half-sum for q=wq*16+cc
    float* sco = (float*)SM;          // 8 waves x [16 q][64 ch] f32 = 32KB
    float* lf = (float*)(SM + 65536); // 8 waves x 16 q (over dead P)
    float* scw = sco + wave * 1024;
#pragma unroll
    for (int ni = 0; ni < 4; ++ni)
#pragma unroll
        for (int r = 0; r < 4; ++r)
            scw[(4 * g + r) * 64 + ni * 16 + cc] = o_acc[ni][r];
    if (g == 0) lf[wave * 16 + cc] = l_acc;
    __syncthreads();
    int q = tid >> 3, c0 = (tid & 7) * 8;   // q 0..63, ch base 0..56
    int wqq = q >> 4, qr = q & 15;
    float l = lf[(wqq * 2) * 16 + qr] + lf[(wqq * 2 + 1) * 16 + qr];
    float inv = 1.f / l;
    const float* p0p = sco + (wqq * 2) * 1024 + qr * 64 + c0;
    const float* p1p = sco + (wqq * 2 + 1) * 1024 + qr * 64 + c0;
    bf16x8 o1;
#pragma unroll
    for (int e = 0; e < 2; ++e) {
        float4 v0 = *(const float4*)(p0p + e * 4);
        float4 v1 = *(const float4*)(p1p + e * 4);
        o1[e * 4 + 0] = (bf16)((v0.x + v1.x) * inv);
        o1[e * 4 + 1] = (bf16)((v0.y + v1.y) * inv);
        o1[e * 4 + 2] = (bf16)((v0.z + v1.z) * inv);
        o1[e * 4 + 3] = (bf16)((v0.w + v1.w) * inv);
    }
    *(bf16x8*)(Op + ((size_t)b * T_ + qrow0 + q) * 512 + h * 64 + c0) = o1;
}

// ---------------------------------------------------------------------------
extern "C" void kernel_launch(void* const* d_in, const int* in_sizes, int n_in,
                              void* d_out, int out_size, void* d_ws, size_t ws_size,
                              hipStream_t stream) {
    const float* x_in    = (const float*)d_in[0];
    const float* cond_k  = (const float*)d_in[1];
    const float* cond_v  = (const float*)d_in[2];
    const float* qkv_w   = (const float*)d_in[3];
    const float* qkv_b   = (const float*)d_in[4];
    const float* attn_w  = (const float*)d_in[5];
    const float* attn_b  = (const float*)d_in[6];
    const float* cross_w = (const float*)d_in[7];
    const float* cross_b = (const float*)d_in[8];
    const float* fc_w    = (const float*)d_in[9];
    const float* fc_b    = (const float*)d_in[10];
    const float* mlp_w   = (const float*)d_in[11];
    const float* mlp_b   = (const float*)d_in[12];
    const float* ln1_g   = (const float*)d_in[13];
    const float* ln1_b   = (const float*)d_in[14];
    const float* ln3_g   = (const float*)d_in[15];
    const float* ln3_b   = (const float*)d_in[16];
    const float* ln4_g   = (const float*)d_in[17];
    const float* ln4_b   = (const float*)d_in[18];

    const int L = 4, T = 2048, S = 512, W = 512;
    const int M = 2 * T;  // B*T rows

    char* ws = (char*)d_ws;
    size_t off = 0;
    auto carve = [&](size_t bytes) -> char* {
        char* p = ws + off;
        off += (bytes + 255) & ~(size_t)255;
        return p;
    };
    bf16* wqkv  = (bf16*)carve((size_t)L * 1536 * 512 * 2);
    bf16* wattn = (bf16*)carve((size_t)L * 512 * 512 * 2);
    bf16* wcrs  = (bf16*)carve((size_t)L * 512 * 512 * 2);
    bf16* wfc   = (bf16*)carve((size_t)L * 2048 * 512 * 2);
    bf16* wmlp  = (bf16*)carve((size_t)L * 512 * 2048 * 2);
    bf16* ckb   = (bf16*)carve((size_t)2 * S * W * 2);
    bf16* VTs   = (bf16*)carve((size_t)16 * 64 * T * 2);   // self V^T per layer
    bf16* VTc   = (bf16*)carve((size_t)16 * 64 * S * 2);   // cross V^T (once)
    bf16* hbuf  = (bf16*)carve((size_t)M * 512 * 2);
    bf16* qkvb  = (bf16*)carve((size_t)M * 1536 * 2);
    bf16* abuf  = (bf16*)carve((size_t)M * 512 * 2);
    bf16* fcb   = (bf16*)carve((size_t)M * 2048 * 2);

    dim3 tb(32, 8);
    wtrans_kernel<<<dim3(1536 / 32, 512 / 32, L), tb, 0, stream>>>(qkv_w, wqkv, 512, 1536);
    wtrans_kernel<<<dim3(512 / 32, 512 / 32, L), tb, 0, stream>>>(attn_w, wattn, 512, 512);
    wtrans_kernel<<<dim3(512 / 32, 512 / 32, L), tb, 0, stream>>>(cross_w, wcrs, 512, 512);
    wtrans_kernel<<<dim3(2048 / 32, 512 / 32, L), tb, 0, stream>>>(fc_w, wfc, 512, 2048);
    wtrans_kernel<<<dim3(512 / 32, 2048 / 32, L), tb, 0, stream>>>(mlp_w, wmlp, 2048, 512);
    cvt_kernel<<<(2 * S * W) / 2048, 256, 0, stream>>>(cond_k, ckb, 2 * S * W);
    vtrans_cross<<<dim3(S / 64, 16), 256, 0, stream>>>(cond_v, VTc, S);

    float* x = (float*)d_out;
    hipMemcpyAsync(x, (const void*)x_in, (size_t)M * W * sizeof(float),
                   hipMemcpyDeviceToDevice, stream);

    const int nAttn = 16 * (T / 64);        // 512 blocks
    for (int i = 0; i < L; ++i) {
        // ---- self-attention sub-block ----
        ln_kernel<<<M / 4, 256, 0, stream>>>(x, ln1_g + i * 512, ln1_b + i * 512, hbuf);
        gemm_kernel<0, 64><<<(M / 64) * (1536 / 128), 256, 0, stream>>>(
            hbuf, wqkv + (size_t)i * 1536 * 512, qkv_b + i * 1536, nullptr, qkvb,
            M, 1536, 512);
        vtrans_self<<<dim3(T / 64, 16), 256, 0, stream>>>(qkvb, VTs, T);
        attn_kernel<<<nAttn, 512, 0, stream>>>(
            qkvb, 1536, 192, qkvb + 64, 1536, 192, VTs, T,
            abuf, T, T);
        gemm_kernel<2, 32><<<(M / 32) * (512 / 128), 256, 0, stream>>>(
            abuf, wattn + (size_t)i * 512 * 512, attn_b + i * 512, x, x,
            M, 512, 512);
        // ---- cross-attention sub-block ----
        ln_kernel<<<M / 4, 256, 0, stream>>>(x, ln3_g + i * 512, ln3_b + i * 512, hbuf);
        attn_kernel<<<nAttn, 512, 0, stream>>>(
            hbuf, 512, 64, ckb, 512, 64, VTc, S,
            abuf, T, S);
        gemm_kernel<2, 32><<<(M / 32) * (512 / 128), 256, 0, stream>>>(
            abuf, wcrs + (size_t)i * 512 * 512, cross_b + i * 512, x, x,
            M, 512, 512);
        // ---- MLP sub-block ----
        ln_kernel<<<M / 4, 256, 0, stream>>>(x, ln4_g + i * 512, ln4_b + i * 512, hbuf);
        gemm_kernel<1, 128><<<(M / 128) * (2048 / 128), 256, 0, stream>>>(
            hbuf, wfc + (size_t)i * 2048 * 512, fc_b + i * 2048, nullptr, fcb,
            M, 2048, 512);
        gemm_kernel<2, 32><<<(M / 32) * (512 / 128), 256, 0, stream>>>(
            fcb, wmlp + (size_t)i * 512 * 2048, mlp_b + i * 512, x, x,
            M, 512, 2048);
    }
}

// Round 12
// 613.742 us; speedup vs baseline: 1.0524x; 1.0404x over previous
//
#include <hip/hip_runtime.h>
#include <hip/hip_bf16.h>
#include <cstdint>

// ---------------------------------------------------------------------------
// Model: 4x [LN -> QKV -> self-attn -> proj+res -> LN -> cross-attn ->
//            proj+res -> LN -> FC+GELU -> proj+res]
// B=2 T=2048 S=512 W=512 H=8 ch=64, all matmuls bf16 MFMA 16x16x32, fp32 accum.
// ---------------------------------------------------------------------------

typedef __bf16 bf16;
typedef __bf16 bf16x8 __attribute__((ext_vector_type(8)));
typedef float f32x4 __attribute__((ext_vector_type(4)));

#define AS1(p) ((__attribute__((address_space(1))) void*)(uintptr_t)(p))
#define AS3(p) ((__attribute__((address_space(3))) void*)(p))

__device__ __forceinline__ unsigned short bf2us(bf16 v) {
    return __builtin_bit_cast(unsigned short, v);
}

// counted-vmcnt barrier (GEMM pipeline): wait until <=N outstanding, barrier.
template <int N>
__device__ __forceinline__ void vmbar() {
    if constexpr (N == 0)      asm volatile("s_waitcnt vmcnt(0)\n\ts_barrier" ::: "memory");
    else if constexpr (N == 3) asm volatile("s_waitcnt vmcnt(3)\n\ts_barrier" ::: "memory");
    else if constexpr (N == 5) asm volatile("s_waitcnt vmcnt(5)\n\ts_barrier" ::: "memory");
    else if constexpr (N == 6) asm volatile("s_waitcnt vmcnt(6)\n\ts_barrier" ::: "memory");
    else if constexpr (N == 8) asm volatile("s_waitcnt vmcnt(8)\n\ts_barrier" ::: "memory");
    __builtin_amdgcn_sched_barrier(0);
}
__device__ __forceinline__ void plainbar() {
    asm volatile("s_barrier" ::: "memory");
    __builtin_amdgcn_sched_barrier(0);
}

// ---------------- LayerNorm (f32 in) -> bf16 out, W=512 -------------------
__global__ __launch_bounds__(256) void ln_kernel(const float* __restrict__ x,
                                                 const float* __restrict__ gam,
                                                 const float* __restrict__ bet,
                                                 bf16* __restrict__ h) {
    int row  = blockIdx.x * 4 + (threadIdx.x >> 6);
    int lane = threadIdx.x & 63;
    const float4* xr = (const float4*)(x + (size_t)row * 512) + lane * 2;
    float4 a = xr[0], b = xr[1];
    float s  = a.x + a.y + a.z + a.w + b.x + b.y + b.z + b.w;
    float ss = a.x * a.x + a.y * a.y + a.z * a.z + a.w * a.w +
               b.x * b.x + b.y * b.y + b.z * b.z + b.w * b.w;
#pragma unroll
    for (int off = 1; off < 64; off <<= 1) {
        s  += __shfl_xor(s, off);
        ss += __shfl_xor(ss, off);
    }
    float mean = s * (1.f / 512.f);
    float var  = ss * (1.f / 512.f) - mean * mean;
    float rstd = rsqrtf(fmaxf(var, 0.f) + 1e-5f);
    const float4* gr = (const float4*)gam + lane * 2;
    const float4* br = (const float4*)bet + lane * 2;
    float4 g0 = gr[0], g1 = gr[1], b0 = br[0], b1 = br[1];
    bf16x8 hv;
    hv[0] = (bf16)((a.x - mean) * rstd * g0.x + b0.x);
    hv[1] = (bf16)((a.y - mean) * rstd * g0.y + b0.y);
    hv[2] = (bf16)((a.z - mean) * rstd * g0.z + b0.z);
    hv[3] = (bf16)((a.w - mean) * rstd * g0.w + b0.w);
    hv[4] = (bf16)((b.x - mean) * rstd * g1.x + b1.x);
    hv[5] = (bf16)((b.y - mean) * rstd * g1.y + b1.y);
    hv[6] = (bf16)((b.z - mean) * rstd * g1.z + b1.z);
    hv[7] = (bf16)((b.w - mean) * rstd * g1.w + b1.w);
    *(bf16x8*)(h + (size_t)row * 512 + lane * 8) = hv;
}

// ------------- transpose+convert: in f32 [L][K][N] -> out bf16 [L][N][K] ---
__global__ void wtrans_kernel(const float* __restrict__ in, bf16* __restrict__ out,
                              int K, int N) {
    __shared__ float tile[32][33];
    int n0 = blockIdx.x * 32, k0 = blockIdx.y * 32;
    const float* ip = in + (size_t)blockIdx.z * K * N;
    bf16* op = out + (size_t)blockIdx.z * N * K;
#pragma unroll
    for (int i = threadIdx.y; i < 32; i += 8)
        tile[i][threadIdx.x] = ip[(size_t)(k0 + i) * N + n0 + threadIdx.x];
    __syncthreads();
#pragma unroll
    for (int i = threadIdx.y; i < 32; i += 8)
        op[(size_t)(n0 + i) * K + k0 + threadIdx.x] = (bf16)tile[threadIdx.x][i];
}

// ------------- elementwise f32 -> bf16 ------------------------------------
__global__ void cvt_kernel(const float* __restrict__ in, bf16* __restrict__ out, int n) {
    int i = (blockIdx.x * 256 + threadIdx.x) * 8;
    if (i + 8 <= n) {
        const float4* p = (const float4*)(in + i);
        float4 a = p[0], b = p[1];
        bf16x8 v;
        v[0] = (bf16)a.x; v[1] = (bf16)a.y; v[2] = (bf16)a.z; v[3] = (bf16)a.w;
        v[4] = (bf16)b.x; v[5] = (bf16)b.y; v[6] = (bf16)b.z; v[7] = (bf16)b.w;
        *(bf16x8*)(out + i) = v;
    }
}

// ------------- V transpose (self): qkvb V-slice -> VT[bh][64][T] bf16 ------
__global__ __launch_bounds__(256) void vtrans_self(const bf16* __restrict__ qkvb,
                                                   bf16* __restrict__ VTs, int T_) {
    __shared__ bf16 tl[64][66];
    int tb = blockIdx.x * 64;
    int bh = blockIdx.y;
    int b = bh >> 3, h = bh & 7;
    int tid = threadIdx.x;
#pragma unroll
    for (int e = 0; e < 2; ++e) {
        int idx = e * 256 + tid;         // 0..511: t x 8ch-groups
        int t = idx >> 3, ci = (idx & 7) * 8;
        bf16x8 v = *(const bf16x8*)(qkvb + ((size_t)b * T_ + tb + t) * 1536 +
                                    h * 192 + 128 + ci);
#pragma unroll
        for (int j = 0; j < 8; ++j) tl[ci + j][t] = v[j];
    }
    __syncthreads();
#pragma unroll
    for (int e = 0; e < 2; ++e) {
        int idx = e * 256 + tid;
        int ch = idx >> 3, ti = (idx & 7) * 8;
        bf16x8 v;
#pragma unroll
        for (int j = 0; j < 8; ++j) v[j] = tl[ch][ti + j];
        *(bf16x8*)(VTs + ((size_t)bh * 64 + ch) * T_ + tb + ti) = v;
    }
}

// ------------- V transpose (cross): cond_v f32 -> VT[bh][64][S] bf16 -------
__global__ __launch_bounds__(256) void vtrans_cross(const float* __restrict__ cv,
                                                    bf16* __restrict__ VTc, int S_) {
    __shared__ bf16 tl[64][66];
    int sb = blockIdx.x * 64;
    int bh = blockIdx.y;
    int b = bh >> 3, h = bh & 7;
    int tid = threadIdx.x;
#pragma unroll
    for (int e = 0; e < 4; ++e) {
        int idx = e * 256 + tid;         // 0..1023: s x 16 ch-groups(4)
        int s = idx >> 4, ci = (idx & 15) * 4;
        float4 v = *(const float4*)(cv + ((size_t)b * S_ + sb + s) * 512 + h * 64 + ci);
        tl[ci + 0][s] = (bf16)v.x; tl[ci + 1][s] = (bf16)v.y;
        tl[ci + 2][s] = (bf16)v.z; tl[ci + 3][s] = (bf16)v.w;
    }
    __syncthreads();
#pragma unroll
    for (int e = 0; e < 2; ++e) {
        int idx = e * 256 + tid;
        int ch = idx >> 3, si = (idx & 7) * 8;
        bf16x8 v;
#pragma unroll
        for (int j = 0; j < 8; ++j) v[j] = tl[ch][si + j];
        *(bf16x8*)(VTc + ((size_t)bh * 64 + ch) * S_ + sb + si) = v;
    }
}

// ------------- GEMM: C = A[M][K] @ Bt[N][K]^T + bias, BM x BN tile ---------
// Depth-2 counted-vmcnt pipeline (R9, proven). 4 waves in 2x2 layout:
// wave covers BM/2 rows x BN/2 cols.
template <int EPI, int BM, int BN>
__global__ __launch_bounds__(256) void gemm_kernel(const bf16* __restrict__ A,
                                                   const bf16* __restrict__ Bt,
                                                   const float* __restrict__ bias,
                                                   const float* res, void* out,
                                                   int M, int N, int K) {
    constexpr int MI = BM / 32;          // row frags per wave
    constexpr int NI = BN / 32;          // col frags per wave
    constexpr int LPW = BM / 32 + BN / 32;  // vmem insts per thread per stage
    constexpr int ABYTES = BM * 128;     // bytes per A buffer
    constexpr int BBYTES = BN * 128;     // bytes per B buffer
    __shared__ __align__(16) bf16 As[2 * BM * 64];
    __shared__ __align__(16) bf16 Bs[2 * BN * 64];
    int tiles_n = N / BN;
    int bid = blockIdx.x;
    int cpx = gridDim.x >> 3;           // grid % 8 == 0 for all our launches
    bid = (bid & 7) * cpx + (bid >> 3); // XCD-aware swizzle
    int bm = bid / tiles_n, bn = bid % tiles_n;
    int tid = threadIdx.x, wave = tid >> 6, lane = tid & 63;
    int wm = wave >> 1, wn = wave & 1;
    int g = lane >> 4, cc = lane & 15;
    f32x4 acc[MI][NI] = {};
    const bf16* Ag = A + (size_t)(bm * BM) * K;
    const bf16* Bg = Bt + (size_t)(bn * BN) * K;
    int scol = (tid & 7) * 8;  // element offset within 64-wide row

    auto stage = [&](int k0, int buf) {
#pragma unroll
        for (int e = 0; e < BM / 32; ++e) {
            int row = (e * 256 + tid) >> 3;
            __builtin_amdgcn_global_load_lds(AS1(Ag + (size_t)row * K + k0 + scol),
                                             AS3((char*)As + buf * ABYTES + e * 4096 + wave * 1024),
                                             16, 0, 0);
        }
#pragma unroll
        for (int e = 0; e < BN / 32; ++e) {
            int row = (e * 256 + tid) >> 3;
            __builtin_amdgcn_global_load_lds(AS1(Bg + (size_t)row * K + k0 + scol),
                                             AS3((char*)Bs + buf * BBYTES + e * 4096 + wave * 1024),
                                             16, 0, 0);
        }
    };

    int nk = K >> 6;                     // >= 8 for all our shapes
    stage(0, 0);
    stage(64, 1);
    for (int t = 0; t < nk; ++t) {
        if (t + 1 < nk) vmbar<LPW>(); else vmbar<0>();
        const bf16* Ab = As + (t & 1) * (BM * 64);
        const bf16* Bb = Bs + (t & 1) * (BN * 64);
#pragma unroll
        for (int kk = 0; kk < 2; ++kk) {
            bf16x8 af[MI], bfr[NI];
#pragma unroll
            for (int mi = 0; mi < MI; ++mi)
                af[mi] = *(const bf16x8*)(Ab + (wm * (BM / 2) + mi * 16 + cc) * 64 + kk * 32 + g * 8);
#pragma unroll
            for (int ni = 0; ni < NI; ++ni)
                bfr[ni] = *(const bf16x8*)(Bb + (wn * (BN / 2) + ni * 16 + cc) * 64 + kk * 32 + g * 8);
#pragma unroll
            for (int mi = 0; mi < MI; ++mi)
#pragma unroll
                for (int ni = 0; ni < NI; ++ni)
                    acc[mi][ni] = __builtin_amdgcn_mfma_f32_16x16x32_bf16(
                        af[mi], bfr[ni], acc[mi][ni], 0, 0, 0);
        }
        plainbar();                       // everyone done reading buf[t&1]
        if (t + 2 < nk) stage((t + 2) * 64, t & 1);
    }
    // epilogue: D[m = 4*(lane>>4)+r][n = lane&15] per 16x16 fragment
    int m0 = bm * BM + wm * (BM / 2);
    int n0 = bn * BN + wn * (BN / 2);
#pragma unroll
    for (int ni = 0; ni < NI; ++ni) {
        int n = n0 + ni * 16 + cc;
        float bv = bias[n];
#pragma unroll
        for (int mi = 0; mi < MI; ++mi) {
#pragma unroll
            for (int r = 0; r < 4; ++r) {
                int m = m0 + mi * 16 + g * 4 + r;
                float v = acc[mi][ni][r] + bv;
                if (EPI == 1) v = 0.5f * v * (1.f + erff(v * 0.70710678118654752f));
                if (EPI == 2)
                    ((float*)out)[(size_t)m * N + n] = res[(size_t)m * N + n] + v;
                else
                    ((bf16*)out)[(size_t)m * N + n] = (bf16)v;
            }
        }
    }
}

// ------------- flash attention v9b: R11 structure + cvt_pk P-pack ----------
// Block = 64 q, 8 waves, KVBLK=128, ONE barrier per 128 of S. Wave (wq,ws):
// q-rows wq*16..+15, s-half ws. Swapped QK^T, no-max softmax (|s|<~1).
// P packed with v_cvt_pk_bf16_f32 (T12). LDS 80KB -> 2 blocks/CU.
__global__ __launch_bounds__(512) void attn_kernel(
    const bf16* __restrict__ Qp, int q_rs, int q_hs,
    const bf16* __restrict__ Kp, int k_rs, int k_hs,
    const bf16* __restrict__ Vt, int vt_s,
    bf16* __restrict__ Op, int T_, int S_) {
    __shared__ __align__(16) char SM[81920];
    // [0,32768): K dbuf 2 x [128 s][64 ch], 128B rows, chunk^(row&7)
    // [32768,65536): V^T dbuf 2 x [64 ch][128 s], 256B rows, chunk^(row&15)
    // [65536,81920): P, 8 waves x 2KB ([16 q][64 s], 128B rows, chunk^(cc&7))

    int numQ = T_ >> 6;
    int phys = blockIdx.x;
    int cpx = gridDim.x >> 3;              // grid % 8 == 0
    int bid = (phys & 7) * cpx + (phys >> 3);
    int qb = bid % numQ;
    int bh = bid / numQ;
    int b = bh >> 3, h = bh & 7;
    int tid = threadIdx.x, wave = tid >> 6, lane = tid & 63;
    int wq = wave >> 1, ws = wave & 1;     // q-block, s-half
    int g = lane >> 4, cc = lane & 15;
    int qrow0 = qb * 64;
    int swz = cc & 7;

    const bf16* Qb = Qp + ((size_t)b * T_ + qrow0 + wq * 16) * q_rs + h * q_hs;
    const bf16* Kb = Kp + ((size_t)b * S_) * k_rs + h * k_hs;
    const bf16* Vtb = Vt + (size_t)bh * 64 * vt_s;

    // Q fragments (B-operand): lane holds Q[q=wq*16+cc][k=kk*32+8g+j],
    // pre-scaled by (1/sqrt(ch))*log2(e) so softmax is exp2() directly.
    const float QSC = 0.125f * 1.44269504088896f;
    bf16x8 qf[2];
#pragma unroll
    for (int kk = 0; kk < 2; ++kk) {
        bf16x8 raw = *(const bf16x8*)(Qb + (size_t)cc * q_rs + kk * 32 + g * 8);
        bf16x8 sc;
#pragma unroll
        for (int j = 0; j < 8; ++j) sc[j] = (bf16)((float)raw[j] * QSC);
        qf[kk] = sc;
    }

    float l_acc = 0.f;
    f32x4 o_acc[4] = {};
    char* Pw = SM + 65536 + wave * 2048;

    auto stage = [&](int s0, int buf) {
        // K tile 128x64: 2 x 16B per thread; source pre-swizzled.
#pragma unroll
        for (int e = 0; e < 2; ++e) {
            int L = e * 512 + tid;
            int row = L >> 3, cp = L & 7;
            int col = (cp ^ (row & 7)) * 8;
            __builtin_amdgcn_global_load_lds(AS1(Kb + (size_t)(s0 + row) * k_rs + col),
                                             AS3(SM + buf * 16384 + e * 8192 + wave * 1024), 16, 0, 0);
        }
        // V^T tile 64x128 (256B rows): 2 x 16B per thread; source pre-swizzled.
#pragma unroll
        for (int e = 0; e < 2; ++e) {
            int L = e * 512 + tid;
            int row = L >> 4, cp = L & 15;
            int scl = (cp ^ (row & 15)) * 8;
            __builtin_amdgcn_global_load_lds(AS1(Vtb + (size_t)row * vt_s + s0 + scl),
                                             AS3(SM + 32768 + buf * 16384 + e * 8192 + wave * 1024), 16, 0, 0);
        }
    };

    stage(0, 0);
    __syncthreads();

    int nt = S_ >> 7;
    int cur = 0;
    for (int t = 0; t < nt; ++t) {
        if (t + 1 < nt) stage((t + 1) * 128, cur ^ 1);
        char* kbc = SM + cur * 16384;
        char* vbc = SM + 32768 + cur * 16384;
        // QK^T (swapped): sf[sn][r] = S^T[s=ws*64+sn*16+4g+r][q=wq*16+cc]
        f32x4 sf[4] = {};
        __builtin_amdgcn_s_setprio(1);
#pragma unroll
        for (int kk = 0; kk < 2; ++kk)
#pragma unroll
            for (int sn = 0; sn < 4; ++sn) {
                int row = ws * 64 + sn * 16 + cc;
                bf16x8 kf = *(const bf16x8*)(kbc + row * 128 + (((kk * 4 + g) ^ (row & 7)) << 4));
                sf[sn] = __builtin_amdgcn_mfma_f32_16x16x32_bf16(kf, qf[kk], sf[sn], 0, 0, 0);
            }
        __builtin_amdgcn_s_setprio(0);
        // no-max softmax: p = exp2(s); pack with v_cvt_pk_bf16_f32 (T12)
#pragma unroll
        for (int sn = 0; sn < 4; ++sn) {
            float p0 = exp2f(sf[sn][0]), p1 = exp2f(sf[sn][1]);
            float p2 = exp2f(sf[sn][2]), p3 = exp2f(sf[sn][3]);
            l_acc += (p0 + p1) + (p2 + p3);
            uint32_t u01, u23;
            asm("v_cvt_pk_bf16_f32 %0, %1, %2" : "=v"(u01) : "v"(p0), "v"(p1));
            asm("v_cvt_pk_bf16_f32 %0, %1, %2" : "=v"(u23) : "v"(p2), "v"(p3));
            // P[q=cc][s_local=sn*16+4g+r]: chunk = sn*2+(g>>1), ^swz
            char* pb = Pw + cc * 128 + (((sn * 2 + (g >> 1)) ^ swz) << 4) + (g & 1) * 8;
            uint2 uu; uu.x = u01; uu.y = u23;
            *(uint2*)pb = uu;
        }
        // PV over the wave's 64-s half: o[q][ch] += P[q][s] * V^T[ch][s]
        __builtin_amdgcn_s_setprio(1);
#pragma unroll
        for (int kk = 0; kk < 2; ++kk) {
            bf16x8 pa = *(const bf16x8*)(Pw + cc * 128 + (((kk * 4 + g) ^ swz) << 4));
#pragma unroll
            for (int ni = 0; ni < 4; ++ni) {
                int vrow = ni * 16 + cc;
                bf16x8 vf = *(const bf16x8*)(vbc + vrow * 256 +
                                             (((ws * 8 + kk * 4 + g) ^ (vrow & 15)) << 4));
                o_acc[ni] = __builtin_amdgcn_mfma_f32_16x16x32_bf16(pa, vf, o_acc[ni], 0, 0, 0);
            }
        }
        __builtin_amdgcn_s_setprio(0);
        __syncthreads();  // ONE barrier per 128-tile: release bufs + drain stage
        cur ^= 1;
    }

    // ---- cross-half combine (ws partials -> full), in LDS ----
    l_acc += __shfl_xor(l_acc, 16);
    l_acc += __shfl_xor(l_acc, 32);   // lane (g,cc): full half-sum for q=wq*16+cc
    float* sco = (float*)SM;          // 8 waves x [16 q][64 ch] f32 = 32KB
    float* lf = (float*)(SM + 65536); // 8 waves x 16 q (over dead P)
    float* scw = sco + wave * 1024;
#pragma unroll
    for (int ni = 0; ni < 4; ++ni)
#pragma unroll
        for (int r = 0; r < 4; ++r)
            scw[(4 * g + r) * 64 + ni * 16 + cc] = o_acc[ni][r];
    if (g == 0) lf[wave * 16 + cc] = l_acc;
    __syncthreads();
    int q = tid >> 3, c0 = (tid & 7) * 8;   // q 0..63, ch base 0..56
    int wqq = q >> 4, qr = q & 15;
    float l = lf[(wqq * 2) * 16 + qr] + lf[(wqq * 2 + 1) * 16 + qr];
    float inv = 1.f / l;
    const float* p0p = sco + (wqq * 2) * 1024 + qr * 64 + c0;
    const float* p1p = sco + (wqq * 2 + 1) * 1024 + qr * 64 + c0;
    bf16x8 o1;
#pragma unroll
    for (int e = 0; e < 2; ++e) {
        float4 v0 = *(const float4*)(p0p + e * 4);
        float4 v1 = *(const float4*)(p1p + e * 4);
        o1[e * 4 + 0] = (bf16)((v0.x + v1.x) * inv);
        o1[e * 4 + 1] = (bf16)((v0.y + v1.y) * inv);
        o1[e * 4 + 2] = (bf16)((v0.z + v1.z) * inv);
        o1[e * 4 + 3] = (bf16)((v0.w + v1.w) * inv);
    }
    *(bf16x8*)(Op + ((size_t)b * T_ + qrow0 + q) * 512 + h * 64 + c0) = o1;
}

// ---------------------------------------------------------------------------
extern "C" void kernel_launch(void* const* d_in, const int* in_sizes, int n_in,
                              void* d_out, int out_size, void* d_ws, size_t ws_size,
                              hipStream_t stream) {
    const float* x_in    = (const float*)d_in[0];
    const float* cond_k  = (const float*)d_in[1];
    const float* cond_v  = (const float*)d_in[2];
    const float* qkv_w   = (const float*)d_in[3];
    const float* qkv_b   = (const float*)d_in[4];
    const float* attn_w  = (const float*)d_in[5];
    const float* attn_b  = (const float*)d_in[6];
    const float* cross_w = (const float*)d_in[7];
    const float* cross_b = (const float*)d_in[8];
    const float* fc_w    = (const float*)d_in[9];
    const float* fc_b    = (const float*)d_in[10];
    const float* mlp_w   = (const float*)d_in[11];
    const float* mlp_b   = (const float*)d_in[12];
    const float* ln1_g   = (const float*)d_in[13];
    const float* ln1_b   = (const float*)d_in[14];
    const float* ln3_g   = (const float*)d_in[15];
    const float* ln3_b   = (const float*)d_in[16];
    const float* ln4_g   = (const float*)d_in[17];
    const float* ln4_b   = (const float*)d_in[18];

    const int L = 4, T = 2048, S = 512, W = 512;
    const int M = 2 * T;  // B*T rows

    char* ws = (char*)d_ws;
    size_t off = 0;
    auto carve = [&](size_t bytes) -> char* {
        char* p = ws + off;
        off += (bytes + 255) & ~(size_t)255;
        return p;
    };
    bf16* wqkv  = (bf16*)carve((size_t)L * 1536 * 512 * 2);
    bf16* wattn = (bf16*)carve((size_t)L * 512 * 512 * 2);
    bf16* wcrs  = (bf16*)carve((size_t)L * 512 * 512 * 2);
    bf16* wfc   = (bf16*)carve((size_t)L * 2048 * 512 * 2);
    bf16* wmlp  = (bf16*)carve((size_t)L * 512 * 2048 * 2);
    bf16* ckb   = (bf16*)carve((size_t)2 * S * W * 2);
    bf16* VTs   = (bf16*)carve((size_t)16 * 64 * T * 2);   // self V^T per layer
    bf16* VTc   = (bf16*)carve((size_t)16 * 64 * S * 2);   // cross V^T (once)
    bf16* hbuf  = (bf16*)carve((size_t)M * 512 * 2);
    bf16* qkvb  = (bf16*)carve((size_t)M * 1536 * 2);
    bf16* abuf  = (bf16*)carve((size_t)M * 512 * 2);
    bf16* fcb   = (bf16*)carve((size_t)M * 2048 * 2);

    dim3 tb(32, 8);
    wtrans_kernel<<<dim3(1536 / 32, 512 / 32, L), tb, 0, stream>>>(qkv_w, wqkv, 512, 1536);
    wtrans_kernel<<<dim3(512 / 32, 512 / 32, L), tb, 0, stream>>>(attn_w, wattn, 512, 512);
    wtrans_kernel<<<dim3(512 / 32, 512 / 32, L), tb, 0, stream>>>(cross_w, wcrs, 512, 512);
    wtrans_kernel<<<dim3(2048 / 32, 512 / 32, L), tb, 0, stream>>>(fc_w, wfc, 512, 2048);
    wtrans_kernel<<<dim3(512 / 32, 2048 / 32, L), tb, 0, stream>>>(mlp_w, wmlp, 2048, 512);
    cvt_kernel<<<(2 * S * W) / 2048, 256, 0, stream>>>(cond_k, ckb, 2 * S * W);
    vtrans_cross<<<dim3(S / 64, 16), 256, 0, stream>>>(cond_v, VTc, S);

    float* x = (float*)d_out;
    hipMemcpyAsync(x, (const void*)x_in, (size_t)M * W * sizeof(float),
                   hipMemcpyDeviceToDevice, stream);

    const int nAttn = 16 * (T / 64);        // 512 blocks
    for (int i = 0; i < L; ++i) {
        // ---- self-attention sub-block ----
        ln_kernel<<<M / 4, 256, 0, stream>>>(x, ln1_g + i * 512, ln1_b + i * 512, hbuf);
        gemm_kernel<0, 64, 128><<<(M / 64) * (1536 / 128), 256, 0, stream>>>(
            hbuf, wqkv + (size_t)i * 1536 * 512, qkv_b + i * 1536, nullptr, qkvb,
            M, 1536, 512);
        vtrans_self<<<dim3(T / 64, 16), 256, 0, stream>>>(qkvb, VTs, T);
        attn_kernel<<<nAttn, 512, 0, stream>>>(
            qkvb, 1536, 192, qkvb + 64, 1536, 192, VTs, T,
            abuf, T, T);
        gemm_kernel<2, 32, 64><<<(M / 32) * (512 / 64), 256, 0, stream>>>(
            abuf, wattn + (size_t)i * 512 * 512, attn_b + i * 512, x, x,
            M, 512, 512);
        // ---- cross-attention sub-block ----
        ln_kernel<<<M / 4, 256, 0, stream>>>(x, ln3_g + i * 512, ln3_b + i * 512, hbuf);
        attn_kernel<<<nAttn, 512, 0, stream>>>(
            hbuf, 512, 64, ckb, 512, 64, VTc, S,
            abuf, T, S);
        gemm_kernel<2, 32, 64><<<(M / 32) * (512 / 64), 256, 0, stream>>>(
            abuf, wcrs + (size_t)i * 512 * 512, cross_b + i * 512, x, x,
            M, 512, 512);
        // ---- MLP sub-block ----
        ln_kernel<<<M / 4, 256, 0, stream>>>(x, ln4_g + i * 512, ln4_b + i * 512, hbuf);
        gemm_kernel<1, 128, 128><<<(M / 128) * (2048 / 128), 256, 0, stream>>>(
            hbuf, wfc + (size_t)i * 2048 * 512, fc_b + i * 2048, nullptr, fcb,
            M, 2048, 512);
        gemm_kernel<2, 32, 64><<<(M / 32) * (512 / 64), 256, 0, stream>>>(
            fcb, wmlp + (size_t)i * 512 * 2048, mlp_b + i * 512, x, x,
            M, 512, 2048);
    }
}

// Round 13
// 612.725 us; speedup vs baseline: 1.0542x; 1.0017x over previous
//
#include <hip/hip_runtime.h>
#include <hip/hip_bf16.h>
#include <cstdint>

// ---------------------------------------------------------------------------
// Model: 4x [LN -> QKV -> self-attn -> proj+res -> LN -> cross-attn ->
//            proj+res -> LN -> FC+GELU -> proj+res]
// B=2 T=2048 S=512 W=512 H=8 ch=64, all matmuls bf16 MFMA 16x16x32, fp32 accum.
// ---------------------------------------------------------------------------

typedef __bf16 bf16;
typedef __bf16 bf16x8 __attribute__((ext_vector_type(8)));
typedef float f32x4 __attribute__((ext_vector_type(4)));

#define AS1(p) ((__attribute__((address_space(1))) void*)(uintptr_t)(p))
#define AS3(p) ((__attribute__((address_space(3))) void*)(p))

__device__ __forceinline__ unsigned short bf2us(bf16 v) {
    return __builtin_bit_cast(unsigned short, v);
}

// counted-vmcnt barrier (GEMM pipeline): wait until <=N outstanding, barrier.
template <int N>
__device__ __forceinline__ void vmbar() {
    if constexpr (N == 0)      asm volatile("s_waitcnt vmcnt(0)\n\ts_barrier" ::: "memory");
    else if constexpr (N == 3) asm volatile("s_waitcnt vmcnt(3)\n\ts_barrier" ::: "memory");
    else if constexpr (N == 5) asm volatile("s_waitcnt vmcnt(5)\n\ts_barrier" ::: "memory");
    else if constexpr (N == 6) asm volatile("s_waitcnt vmcnt(6)\n\ts_barrier" ::: "memory");
    else if constexpr (N == 8) asm volatile("s_waitcnt vmcnt(8)\n\ts_barrier" ::: "memory");
    __builtin_amdgcn_sched_barrier(0);
}
__device__ __forceinline__ void plainbar() {
    asm volatile("s_barrier" ::: "memory");
    __builtin_amdgcn_sched_barrier(0);
}

// ---------------- LayerNorm (f32 in) -> bf16 out, W=512 -------------------
__global__ __launch_bounds__(256) void ln_kernel(const float* __restrict__ x,
                                                 const float* __restrict__ gam,
                                                 const float* __restrict__ bet,
                                                 bf16* __restrict__ h) {
    int row  = blockIdx.x * 4 + (threadIdx.x >> 6);
    int lane = threadIdx.x & 63;
    const float4* xr = (const float4*)(x + (size_t)row * 512) + lane * 2;
    float4 a = xr[0], b = xr[1];
    float s  = a.x + a.y + a.z + a.w + b.x + b.y + b.z + b.w;
    float ss = a.x * a.x + a.y * a.y + a.z * a.z + a.w * a.w +
               b.x * b.x + b.y * b.y + b.z * b.z + b.w * b.w;
#pragma unroll
    for (int off = 1; off < 64; off <<= 1) {
        s  += __shfl_xor(s, off);
        ss += __shfl_xor(ss, off);
    }
    float mean = s * (1.f / 512.f);
    float var  = ss * (1.f / 512.f) - mean * mean;
    float rstd = rsqrtf(fmaxf(var, 0.f) + 1e-5f);
    const float4* gr = (const float4*)gam + lane * 2;
    const float4* br = (const float4*)bet + lane * 2;
    float4 g0 = gr[0], g1 = gr[1], b0 = br[0], b1 = br[1];
    bf16x8 hv;
    hv[0] = (bf16)((a.x - mean) * rstd * g0.x + b0.x);
    hv[1] = (bf16)((a.y - mean) * rstd * g0.y + b0.y);
    hv[2] = (bf16)((a.z - mean) * rstd * g0.z + b0.z);
    hv[3] = (bf16)((a.w - mean) * rstd * g0.w + b0.w);
    hv[4] = (bf16)((b.x - mean) * rstd * g1.x + b1.x);
    hv[5] = (bf16)((b.y - mean) * rstd * g1.y + b1.y);
    hv[6] = (bf16)((b.z - mean) * rstd * g1.z + b1.z);
    hv[7] = (bf16)((b.w - mean) * rstd * g1.w + b1.w);
    *(bf16x8*)(h + (size_t)row * 512 + lane * 8) = hv;
}

// ------- fused residual + LayerNorm: x_out = x_in + t ; h = LN(x_out) ------
// t is the bf16 GEMM output (bias already applied). x stays f32 in registers.
__global__ __launch_bounds__(256) void resln_kernel(const bf16* __restrict__ t,
                                                    const float* __restrict__ xin,
                                                    float* __restrict__ xout,
                                                    const float* __restrict__ gam,
                                                    const float* __restrict__ bet,
                                                    bf16* __restrict__ h) {
    int row  = blockIdx.x * 4 + (threadIdx.x >> 6);
    int lane = threadIdx.x & 63;
    const float4* xr = (const float4*)(xin + (size_t)row * 512) + lane * 2;
    float4 a = xr[0], b = xr[1];
    bf16x8 tv = *(const bf16x8*)(t + (size_t)row * 512 + lane * 8);
    a.x += (float)tv[0]; a.y += (float)tv[1]; a.z += (float)tv[2]; a.w += (float)tv[3];
    b.x += (float)tv[4]; b.y += (float)tv[5]; b.z += (float)tv[6]; b.w += (float)tv[7];
    float4* xw = (float4*)(xout + (size_t)row * 512) + lane * 2;
    xw[0] = a; xw[1] = b;
    float s  = a.x + a.y + a.z + a.w + b.x + b.y + b.z + b.w;
    float ss = a.x * a.x + a.y * a.y + a.z * a.z + a.w * a.w +
               b.x * b.x + b.y * b.y + b.z * b.z + b.w * b.w;
#pragma unroll
    for (int off = 1; off < 64; off <<= 1) {
        s  += __shfl_xor(s, off);
        ss += __shfl_xor(ss, off);
    }
    float mean = s * (1.f / 512.f);
    float var  = ss * (1.f / 512.f) - mean * mean;
    float rstd = rsqrtf(fmaxf(var, 0.f) + 1e-5f);
    const float4* gr = (const float4*)gam + lane * 2;
    const float4* br = (const float4*)bet + lane * 2;
    float4 g0 = gr[0], g1 = gr[1], b0 = br[0], b1 = br[1];
    bf16x8 hv;
    hv[0] = (bf16)((a.x - mean) * rstd * g0.x + b0.x);
    hv[1] = (bf16)((a.y - mean) * rstd * g0.y + b0.y);
    hv[2] = (bf16)((a.z - mean) * rstd * g0.z + b0.z);
    hv[3] = (bf16)((a.w - mean) * rstd * g0.w + b0.w);
    hv[4] = (bf16)((b.x - mean) * rstd * g1.x + b1.x);
    hv[5] = (bf16)((b.y - mean) * rstd * g1.y + b1.y);
    hv[6] = (bf16)((b.z - mean) * rstd * g1.z + b1.z);
    hv[7] = (bf16)((b.w - mean) * rstd * g1.w + b1.w);
    *(bf16x8*)(h + (size_t)row * 512 + lane * 8) = hv;
}

// ------------- transpose+convert: in f32 [L][K][N] -> out bf16 [L][N][K] ---
__global__ void wtrans_kernel(const float* __restrict__ in, bf16* __restrict__ out,
                              int K, int N) {
    __shared__ float tile[32][33];
    int n0 = blockIdx.x * 32, k0 = blockIdx.y * 32;
    const float* ip = in + (size_t)blockIdx.z * K * N;
    bf16* op = out + (size_t)blockIdx.z * N * K;
#pragma unroll
    for (int i = threadIdx.y; i < 32; i += 8)
        tile[i][threadIdx.x] = ip[(size_t)(k0 + i) * N + n0 + threadIdx.x];
    __syncthreads();
#pragma unroll
    for (int i = threadIdx.y; i < 32; i += 8)
        op[(size_t)(n0 + i) * K + k0 + threadIdx.x] = (bf16)tile[threadIdx.x][i];
}

// ------------- elementwise f32 -> bf16 ------------------------------------
__global__ void cvt_kernel(const float* __restrict__ in, bf16* __restrict__ out, int n) {
    int i = (blockIdx.x * 256 + threadIdx.x) * 8;
    if (i + 8 <= n) {
        const float4* p = (const float4*)(in + i);
        float4 a = p[0], b = p[1];
        bf16x8 v;
        v[0] = (bf16)a.x; v[1] = (bf16)a.y; v[2] = (bf16)a.z; v[3] = (bf16)a.w;
        v[4] = (bf16)b.x; v[5] = (bf16)b.y; v[6] = (bf16)b.z; v[7] = (bf16)b.w;
        *(bf16x8*)(out + i) = v;
    }
}

// ------------- V transpose (self): qkvb V-slice -> VT[bh][64][T] bf16 ------
__global__ __launch_bounds__(256) void vtrans_self(const bf16* __restrict__ qkvb,
                                                   bf16* __restrict__ VTs, int T_) {
    __shared__ bf16 tl[64][66];
    int tb = blockIdx.x * 64;
    int bh = blockIdx.y;
    int b = bh >> 3, h = bh & 7;
    int tid = threadIdx.x;
#pragma unroll
    for (int e = 0; e < 2; ++e) {
        int idx = e * 256 + tid;         // 0..511: t x 8ch-groups
        int t = idx >> 3, ci = (idx & 7) * 8;
        bf16x8 v = *(const bf16x8*)(qkvb + ((size_t)b * T_ + tb + t) * 1536 +
                                    h * 192 + 128 + ci);
#pragma unroll
        for (int j = 0; j < 8; ++j) tl[ci + j][t] = v[j];
    }
    __syncthreads();
#pragma unroll
    for (int e = 0; e < 2; ++e) {
        int idx = e * 256 + tid;
        int ch = idx >> 3, ti = (idx & 7) * 8;
        bf16x8 v;
#pragma unroll
        for (int j = 0; j < 8; ++j) v[j] = tl[ch][ti + j];
        *(bf16x8*)(VTs + ((size_t)bh * 64 + ch) * T_ + tb + ti) = v;
    }
}

// ------------- V transpose (cross): cond_v f32 -> VT[bh][64][S] bf16 -------
__global__ __launch_bounds__(256) void vtrans_cross(const float* __restrict__ cv,
                                                    bf16* __restrict__ VTc, int S_) {
    __shared__ bf16 tl[64][66];
    int sb = blockIdx.x * 64;
    int bh = blockIdx.y;
    int b = bh >> 3, h = bh & 7;
    int tid = threadIdx.x;
#pragma unroll
    for (int e = 0; e < 4; ++e) {
        int idx = e * 256 + tid;         // 0..1023: s x 16 ch-groups(4)
        int s = idx >> 4, ci = (idx & 15) * 4;
        float4 v = *(const float4*)(cv + ((size_t)b * S_ + sb + s) * 512 + h * 64 + ci);
        tl[ci + 0][s] = (bf16)v.x; tl[ci + 1][s] = (bf16)v.y;
        tl[ci + 2][s] = (bf16)v.z; tl[ci + 3][s] = (bf16)v.w;
    }
    __syncthreads();
#pragma unroll
    for (int e = 0; e < 2; ++e) {
        int idx = e * 256 + tid;
        int ch = idx >> 3, si = (idx & 7) * 8;
        bf16x8 v;
#pragma unroll
        for (int j = 0; j < 8; ++j) v[j] = tl[ch][si + j];
        *(bf16x8*)(VTc + ((size_t)bh * 64 + ch) * S_ + sb + si) = v;
    }
}

// ------------- GEMM: C = A[M][K] @ Bt[N][K]^T + bias, BM x BN tile ---------
// Depth-2 counted-vmcnt pipeline (R9, proven). 4 waves in 2x2 layout.
// EPI 0: out bf16 = acc+bias
// EPI 1: out bf16 = gelu(acc+bias)
// EPI 2: out f32  = res + acc + bias     (res/out may alias: in-place x)
template <int EPI, int BM, int BN>
__global__ __launch_bounds__(256) void gemm_kernel(const bf16* __restrict__ A,
                                                   const bf16* __restrict__ Bt,
                                                   const float* __restrict__ bias,
                                                   const float* res, void* out,
                                                   int M, int N, int K) {
    constexpr int MI = BM / 32;          // row frags per wave
    constexpr int NI = BN / 32;          // col frags per wave
    constexpr int LPW = BM / 32 + BN / 32;  // vmem insts per thread per stage
    constexpr int ABYTES = BM * 128;     // bytes per A buffer
    constexpr int BBYTES = BN * 128;     // bytes per B buffer
    __shared__ __align__(16) bf16 As[2 * BM * 64];
    __shared__ __align__(16) bf16 Bs[2 * BN * 64];
    int tiles_n = N / BN;
    int bid = blockIdx.x;
    int cpx = gridDim.x >> 3;           // grid % 8 == 0 for all our launches
    bid = (bid & 7) * cpx + (bid >> 3); // XCD-aware swizzle
    int bm = bid / tiles_n, bn = bid % tiles_n;
    int tid = threadIdx.x, wave = tid >> 6, lane = tid & 63;
    int wm = wave >> 1, wn = wave & 1;
    int g = lane >> 4, cc = lane & 15;
    f32x4 acc[MI][NI] = {};
    const bf16* Ag = A + (size_t)(bm * BM) * K;
    const bf16* Bg = Bt + (size_t)(bn * BN) * K;
    int scol = (tid & 7) * 8;  // element offset within 64-wide row

    auto stage = [&](int k0, int buf) {
#pragma unroll
        for (int e = 0; e < BM / 32; ++e) {
            int row = (e * 256 + tid) >> 3;
            __builtin_amdgcn_global_load_lds(AS1(Ag + (size_t)row * K + k0 + scol),
                                             AS3((char*)As + buf * ABYTES + e * 4096 + wave * 1024),
                                             16, 0, 0);
        }
#pragma unroll
        for (int e = 0; e < BN / 32; ++e) {
            int row = (e * 256 + tid) >> 3;
            __builtin_amdgcn_global_load_lds(AS1(Bg + (size_t)row * K + k0 + scol),
                                             AS3((char*)Bs + buf * BBYTES + e * 4096 + wave * 1024),
                                             16, 0, 0);
        }
    };

    int nk = K >> 6;                     // >= 8 for all our shapes
    stage(0, 0);
    stage(64, 1);
    for (int t = 0; t < nk; ++t) {
        if (t + 1 < nk) vmbar<LPW>(); else vmbar<0>();
        const bf16* Ab = As + (t & 1) * (BM * 64);
        const bf16* Bb = Bs + (t & 1) * (BN * 64);
#pragma unroll
        for (int kk = 0; kk < 2; ++kk) {
            bf16x8 af[MI], bfr[NI];
#pragma unroll
            for (int mi = 0; mi < MI; ++mi)
                af[mi] = *(const bf16x8*)(Ab + (wm * (BM / 2) + mi * 16 + cc) * 64 + kk * 32 + g * 8);
#pragma unroll
            for (int ni = 0; ni < NI; ++ni)
                bfr[ni] = *(const bf16x8*)(Bb + (wn * (BN / 2) + ni * 16 + cc) * 64 + kk * 32 + g * 8);
#pragma unroll
            for (int mi = 0; mi < MI; ++mi)
#pragma unroll
                for (int ni = 0; ni < NI; ++ni)
                    acc[mi][ni] = __builtin_amdgcn_mfma_f32_16x16x32_bf16(
                        af[mi], bfr[ni], acc[mi][ni], 0, 0, 0);
        }
        plainbar();                       // everyone done reading buf[t&1]
        if (t + 2 < nk) stage((t + 2) * 64, t & 1);
    }
    // epilogue: D[m = 4*(lane>>4)+r][n = lane&15] per 16x16 fragment
    int m0 = bm * BM + wm * (BM / 2);
    int n0 = bn * BN + wn * (BN / 2);
#pragma unroll
    for (int ni = 0; ni < NI; ++ni) {
        int n = n0 + ni * 16 + cc;
        float bv = bias[n];
#pragma unroll
        for (int mi = 0; mi < MI; ++mi) {
#pragma unroll
            for (int r = 0; r < 4; ++r) {
                int m = m0 + mi * 16 + g * 4 + r;
                float v = acc[mi][ni][r] + bv;
                if (EPI == 1) v = 0.5f * v * (1.f + erff(v * 0.70710678118654752f));
                if (EPI == 2)
                    ((float*)out)[(size_t)m * N + n] = res[(size_t)m * N + n] + v;
                else
                    ((bf16*)out)[(size_t)m * N + n] = (bf16)v;
            }
        }
    }
}

// ------------- flash attention v9b (R12, proven) ---------------------------
// Block = 64 q, 8 waves, KVBLK=128, ONE barrier per 128 of S. Wave (wq,ws):
// q-rows wq*16..+15, s-half ws. Swapped QK^T, no-max softmax (|s|<~1).
// P packed with v_cvt_pk_bf16_f32 (T12). LDS 80KB -> 2 blocks/CU.
__global__ __launch_bounds__(512) void attn_kernel(
    const bf16* __restrict__ Qp, int q_rs, int q_hs,
    const bf16* __restrict__ Kp, int k_rs, int k_hs,
    const bf16* __restrict__ Vt, int vt_s,
    bf16* __restrict__ Op, int T_, int S_) {
    __shared__ __align__(16) char SM[81920];
    // [0,32768): K dbuf 2 x [128 s][64 ch], 128B rows, chunk^(row&7)
    // [32768,65536): V^T dbuf 2 x [64 ch][128 s], 256B rows, chunk^(row&15)
    // [65536,81920): P, 8 waves x 2KB ([16 q][64 s], 128B rows, chunk^(cc&7))

    int numQ = T_ >> 6;
    int phys = blockIdx.x;
    int cpx = gridDim.x >> 3;              // grid % 8 == 0
    int bid = (phys & 7) * cpx + (phys >> 3);
    int qb = bid % numQ;
    int bh = bid / numQ;
    int b = bh >> 3, h = bh & 7;
    int tid = threadIdx.x, wave = tid >> 6, lane = tid & 63;
    int wq = wave >> 1, ws = wave & 1;     // q-block, s-half
    int g = lane >> 4, cc = lane & 15;
    int qrow0 = qb * 64;
    int swz = cc & 7;

    const bf16* Qb = Qp + ((size_t)b * T_ + qrow0 + wq * 16) * q_rs + h * q_hs;
    const bf16* Kb = Kp + ((size_t)b * S_) * k_rs + h * k_hs;
    const bf16* Vtb = Vt + (size_t)bh * 64 * vt_s;

    // Q fragments (B-operand): lane holds Q[q=wq*16+cc][k=kk*32+8g+j],
    // pre-scaled by (1/sqrt(ch))*log2(e) so softmax is exp2() directly.
    const float QSC = 0.125f * 1.44269504088896f;
    bf16x8 qf[2];
#pragma unroll
    for (int kk = 0; kk < 2; ++kk) {
        bf16x8 raw = *(const bf16x8*)(Qb + (size_t)cc * q_rs + kk * 32 + g * 8);
        bf16x8 sc;
#pragma unroll
        for (int j = 0; j < 8; ++j) sc[j] = (bf16)((float)raw[j] * QSC);
        qf[kk] = sc;
    }

    float l_acc = 0.f;
    f32x4 o_acc[4] = {};
    char* Pw = SM + 65536 + wave * 2048;

    auto stage = [&](int s0, int buf) {
        // K tile 128x64: 2 x 16B per thread; source pre-swizzled.
#pragma unroll
        for (int e = 0; e < 2; ++e) {
            int L = e * 512 + tid;
            int row = L >> 3, cp = L & 7;
            int col = (cp ^ (row & 7)) * 8;
            __builtin_amdgcn_global_load_lds(AS1(Kb + (size_t)(s0 + row) * k_rs + col),
                                             AS3(SM + buf * 16384 + e * 8192 + wave * 1024), 16, 0, 0);
        }
        // V^T tile 64x128 (256B rows): 2 x 16B per thread; source pre-swizzled.
#pragma unroll
        for (int e = 0; e < 2; ++e) {
            int L = e * 512 + tid;
            int row = L >> 4, cp = L & 15;
            int scl = (cp ^ (row & 15)) * 8;
            __builtin_amdgcn_global_load_lds(AS1(Vtb + (size_t)row * vt_s + s0 + scl),
                                             AS3(SM + 32768 + buf * 16384 + e * 8192 + wave * 1024), 16, 0, 0);
        }
    };

    stage(0, 0);
    __syncthreads();

    int nt = S_ >> 7;
    int cur = 0;
    for (int t = 0; t < nt; ++t) {
        if (t + 1 < nt) stage((t + 1) * 128, cur ^ 1);
        char* kbc = SM + cur * 16384;
        char* vbc = SM + 32768 + cur * 16384;
        // QK^T (swapped): sf[sn][r] = S^T[s=ws*64+sn*16+4g+r][q=wq*16+cc]
        f32x4 sf[4] = {};
        __builtin_amdgcn_s_setprio(1);
#pragma unroll
        for (int kk = 0; kk < 2; ++kk)
#pragma unroll
            for (int sn = 0; sn < 4; ++sn) {
                int row = ws * 64 + sn * 16 + cc;
                bf16x8 kf = *(const bf16x8*)(kbc + row * 128 + (((kk * 4 + g) ^ (row & 7)) << 4));
                sf[sn] = __builtin_amdgcn_mfma_f32_16x16x32_bf16(kf, qf[kk], sf[sn], 0, 0, 0);
            }
        __builtin_amdgcn_s_setprio(0);
        // no-max softmax: p = exp2(s); pack with v_cvt_pk_bf16_f32 (T12)
#pragma unroll
        for (int sn = 0; sn < 4; ++sn) {
            float p0 = exp2f(sf[sn][0]), p1 = exp2f(sf[sn][1]);
            float p2 = exp2f(sf[sn][2]), p3 = exp2f(sf[sn][3]);
            l_acc += (p0 + p1) + (p2 + p3);
            uint32_t u01, u23;
            asm("v_cvt_pk_bf16_f32 %0, %1, %2" : "=v"(u01) : "v"(p0), "v"(p1));
            asm("v_cvt_pk_bf16_f32 %0, %1, %2" : "=v"(u23) : "v"(p2), "v"(p3));
            // P[q=cc][s_local=sn*16+4g+r]: chunk = sn*2+(g>>1), ^swz
            char* pb = Pw + cc * 128 + (((sn * 2 + (g >> 1)) ^ swz) << 4) + (g & 1) * 8;
            uint2 uu; uu.x = u01; uu.y = u23;
            *(uint2*)pb = uu;
        }
        // PV over the wave's 64-s half: o[q][ch] += P[q][s] * V^T[ch][s]
        __builtin_amdgcn_s_setprio(1);
#pragma unroll
        for (int kk = 0; kk < 2; ++kk) {
            bf16x8 pa = *(const bf16x8*)(Pw + cc * 128 + (((kk * 4 + g) ^ swz) << 4));
#pragma unroll
            for (int ni = 0; ni < 4; ++ni) {
                int vrow = ni * 16 + cc;
                bf16x8 vf = *(const bf16x8*)(vbc + vrow * 256 +
                                             (((ws * 8 + kk * 4 + g) ^ (vrow & 15)) << 4));
                o_acc[ni] = __builtin_amdgcn_mfma_f32_16x16x32_bf16(pa, vf, o_acc[ni], 0, 0, 0);
            }
        }
        __builtin_amdgcn_s_setprio(0);
        __syncthreads();  // ONE barrier per 128-tile: release bufs + drain stage
        cur ^= 1;
    }

    // ---- cross-half combine (ws partials -> full), in LDS ----
    l_acc += __shfl_xor(l_acc, 16);
    l_acc += __shfl_xor(l_acc, 32);   // lane (g,cc): full half-sum for q=wq*16+cc
    float* sco = (float*)SM;          // 8 waves x [16 q][64 ch] f32 = 32KB
    float* lf = (float*)(SM + 65536); // 8 waves x 16 q (over dead P)
    float* scw = sco + wave * 1024;
#pragma unroll
    for (int ni = 0; ni < 4; ++ni)
#pragma unroll
        for (int r = 0; r < 4; ++r)
            scw[(4 * g + r) * 64 + ni * 16 + cc] = o_acc[ni][r];
    if (g == 0) lf[wave * 16 + cc] = l_acc;
    __syncthreads();
    int q = tid >> 3, c0 = (tid & 7) * 8;   // q 0..63, ch base 0..56
    int wqq = q >> 4, qr = q & 15;
    float l = lf[(wqq * 2) * 16 + qr] + lf[(wqq * 2 + 1) * 16 + qr];
    float inv = 1.f / l;
    const float* p0p = sco + (wqq * 2) * 1024 + qr * 64 + c0;
    const float* p1p = sco + (wqq * 2 + 1) * 1024 + qr * 64 + c0;
    bf16x8 o1;
#pragma unroll
    for (int e = 0; e < 2; ++e) {
        float4 v0 = *(const float4*)(p0p + e * 4);
        float4 v1 = *(const float4*)(p1p + e * 4);
        o1[e * 4 + 0] = (bf16)((v0.x + v1.x) * inv);
        o1[e * 4 + 1] = (bf16)((v0.y + v1.y) * inv);
        o1[e * 4 + 2] = (bf16)((v0.z + v1.z) * inv);
        o1[e * 4 + 3] = (bf16)((v0.w + v1.w) * inv);
    }
    *(bf16x8*)(Op + ((size_t)b * T_ + qrow0 + q) * 512 + h * 64 + c0) = o1;
}

// ---------------------------------------------------------------------------
extern "C" void kernel_launch(void* const* d_in, const int* in_sizes, int n_in,
                              void* d_out, int out_size, void* d_ws, size_t ws_size,
                              hipStream_t stream) {
    const float* x_in    = (const float*)d_in[0];
    const float* cond_k  = (const float*)d_in[1];
    const float* cond_v  = (const float*)d_in[2];
    const float* qkv_w   = (const float*)d_in[3];
    const float* qkv_b   = (const float*)d_in[4];
    const float* attn_w  = (const float*)d_in[5];
    const float* attn_b  = (const float*)d_in[6];
    const float* cross_w = (const float*)d_in[7];
    const float* cross_b = (const float*)d_in[8];
    const float* fc_w    = (const float*)d_in[9];
    const float* fc_b    = (const float*)d_in[10];
    const float* mlp_w   = (const float*)d_in[11];
    const float* mlp_b   = (const float*)d_in[12];
    const float* ln1_g   = (const float*)d_in[13];
    const float* ln1_b   = (const float*)d_in[14];
    const float* ln3_g   = (const float*)d_in[15];
    const float* ln3_b   = (const float*)d_in[16];
    const float* ln4_g   = (const float*)d_in[17];
    const float* ln4_b   = (const float*)d_in[18];

    const int L = 4, T = 2048, S = 512, W = 512;
    const int M = 2 * T;  // B*T rows

    char* ws = (char*)d_ws;
    size_t off = 0;
    auto carve = [&](size_t bytes) -> char* {
        char* p = ws + off;
        off += (bytes + 255) & ~(size_t)255;
        return p;
    };
    bf16* wqkv  = (bf16*)carve((size_t)L * 1536 * 512 * 2);
    bf16* wattn = (bf16*)carve((size_t)L * 512 * 512 * 2);
    bf16* wcrs  = (bf16*)carve((size_t)L * 512 * 512 * 2);
    bf16* wfc   = (bf16*)carve((size_t)L * 2048 * 512 * 2);
    bf16* wmlp  = (bf16*)carve((size_t)L * 512 * 2048 * 2);
    bf16* ckb   = (bf16*)carve((size_t)2 * S * W * 2);
    bf16* VTs   = (bf16*)carve((size_t)16 * 64 * T * 2);   // self V^T per layer
    bf16* VTc   = (bf16*)carve((size_t)16 * 64 * S * 2);   // cross V^T (once)
    bf16* hbuf  = (bf16*)carve((size_t)M * 512 * 2);
    bf16* qkvb  = (bf16*)carve((size_t)M * 1536 * 2);
    bf16* abuf  = (bf16*)carve((size_t)M * 512 * 2);
    bf16* fcb   = (bf16*)carve((size_t)M * 2048 * 2);
    bf16* tbuf  = qkvb;  // proj outputs reuse qkvb (dead after attn)

    dim3 tb(32, 8);
    wtrans_kernel<<<dim3(1536 / 32, 512 / 32, L), tb, 0, stream>>>(qkv_w, wqkv, 512, 1536);
    wtrans_kernel<<<dim3(512 / 32, 512 / 32, L), tb, 0, stream>>>(attn_w, wattn, 512, 512);
    wtrans_kernel<<<dim3(512 / 32, 512 / 32, L), tb, 0, stream>>>(cross_w, wcrs, 512, 512);
    wtrans_kernel<<<dim3(2048 / 32, 512 / 32, L), tb, 0, stream>>>(fc_w, wfc, 512, 2048);
    wtrans_kernel<<<dim3(512 / 32, 2048 / 32, L), tb, 0, stream>>>(mlp_w, wmlp, 2048, 512);
    cvt_kernel<<<(2 * S * W) / 2048, 256, 0, stream>>>(cond_k, ckb, 2 * S * W);
    vtrans_cross<<<dim3(S / 64, 16), 256, 0, stream>>>(cond_v, VTc, S);

    float* x = (float*)d_out;   // first written by layer-0 attn-proj resln

    const int nAttn = 16 * (T / 64);        // 512 blocks
    for (int i = 0; i < L; ++i) {
        // ---- self-attention sub-block ----
        if (i == 0)   // later layers: hbuf produced by previous mlp resln
            ln_kernel<<<M / 4, 256, 0, stream>>>(x_in, ln1_g, ln1_b, hbuf);
        gemm_kernel<0, 64, 128><<<(M / 64) * (1536 / 128), 256, 0, stream>>>(
            hbuf, wqkv + (size_t)i * 1536 * 512, qkv_b + i * 1536, nullptr, qkvb,
            M, 1536, 512);
        vtrans_self<<<dim3(T / 64, 16), 256, 0, stream>>>(qkvb, VTs, T);
        attn_kernel<<<nAttn, 512, 0, stream>>>(
            qkvb, 1536, 192, qkvb + 64, 1536, 192, VTs, T,
            abuf, T, T);
        gemm_kernel<0, 32, 64><<<(M / 32) * (512 / 64), 256, 0, stream>>>(
            abuf, wattn + (size_t)i * 512 * 512, attn_b + i * 512, nullptr, tbuf,
            M, 512, 512);
        resln_kernel<<<M / 4, 256, 0, stream>>>(
            tbuf, (i == 0) ? x_in : x, x, ln3_g + i * 512, ln3_b + i * 512, hbuf);
        // ---- cross-attention sub-block ----
        attn_kernel<<<nAttn, 512, 0, stream>>>(
            hbuf, 512, 64, ckb, 512, 64, VTc, S,
            abuf, T, S);
        gemm_kernel<0, 32, 64><<<(M / 32) * (512 / 64), 256, 0, stream>>>(
            abuf, wcrs + (size_t)i * 512 * 512, cross_b + i * 512, nullptr, tbuf,
            M, 512, 512);
        resln_kernel<<<M / 4, 256, 0, stream>>>(
            tbuf, x, x, ln4_g + i * 512, ln4_b + i * 512, hbuf);
        // ---- MLP sub-block ----
        gemm_kernel<1, 128, 128><<<(M / 128) * (2048 / 128), 256, 0, stream>>>(
            hbuf, wfc + (size_t)i * 2048 * 512, fc_b + i * 2048, nullptr, fcb,
            M, 2048, 512);
        if (i + 1 < L) {
            gemm_kernel<0, 32, 64><<<(M / 32) * (512 / 64), 256, 0, stream>>>(
                fcb, wmlp + (size_t)i * 512 * 2048, mlp_b + i * 512, nullptr, tbuf,
                M, 512, 2048);
            resln_kernel<<<M / 4, 256, 0, stream>>>(
                tbuf, x, x, ln1_g + (i + 1) * 512, ln1_b + (i + 1) * 512, hbuf);
        } else {
            gemm_kernel<2, 32, 64><<<(M / 32) * (512 / 64), 256, 0, stream>>>(
                fcb, wmlp + (size_t)i * 512 * 2048, mlp_b + i * 512, x, x,
                M, 512, 2048);
        }
    }
}

// Round 14
// 605.526 us; speedup vs baseline: 1.0667x; 1.0119x over previous
//
#include <hip/hip_runtime.h>
#include <hip/hip_bf16.h>
#include <cstdint>

// ---------------------------------------------------------------------------
// Model: 4x [LN -> QKV -> self-attn -> proj+res -> LN -> cross-attn ->
//            proj+res -> LN -> FC+GELU -> proj+res]
// B=2 T=2048 S=512 W=512 H=8 ch=64, all matmuls bf16 MFMA 16x16x32, fp32 accum.
// ---------------------------------------------------------------------------

typedef __bf16 bf16;
typedef __bf16 bf16x8 __attribute__((ext_vector_type(8)));
typedef float f32x4 __attribute__((ext_vector_type(4)));

#define AS1(p) ((__attribute__((address_space(1))) void*)(uintptr_t)(p))
#define AS3(p) ((__attribute__((address_space(3))) void*)(p))

__device__ __forceinline__ unsigned short bf2us(bf16 v) {
    return __builtin_bit_cast(unsigned short, v);
}

// counted-vmcnt barrier (GEMM pipeline): wait until <=N outstanding, barrier.
template <int N>
__device__ __forceinline__ void vmbar() {
    if constexpr (N == 0)      asm volatile("s_waitcnt vmcnt(0)\n\ts_barrier" ::: "memory");
    else if constexpr (N == 3) asm volatile("s_waitcnt vmcnt(3)\n\ts_barrier" ::: "memory");
    else if constexpr (N == 5) asm volatile("s_waitcnt vmcnt(5)\n\ts_barrier" ::: "memory");
    else if constexpr (N == 6) asm volatile("s_waitcnt vmcnt(6)\n\ts_barrier" ::: "memory");
    else if constexpr (N == 8) asm volatile("s_waitcnt vmcnt(8)\n\ts_barrier" ::: "memory");
    __builtin_amdgcn_sched_barrier(0);
}
__device__ __forceinline__ void plainbar() {
    asm volatile("s_barrier" ::: "memory");
    __builtin_amdgcn_sched_barrier(0);
}

// ---------------- LayerNorm (f32 in) -> bf16 out, W=512 -------------------
__global__ __launch_bounds__(256) void ln_kernel(const float* __restrict__ x,
                                                 const float* __restrict__ gam,
                                                 const float* __restrict__ bet,
                                                 bf16* __restrict__ h) {
    int row  = blockIdx.x * 4 + (threadIdx.x >> 6);
    int lane = threadIdx.x & 63;
    const float4* xr = (const float4*)(x + (size_t)row * 512) + lane * 2;
    float4 a = xr[0], b = xr[1];
    float s  = a.x + a.y + a.z + a.w + b.x + b.y + b.z + b.w;
    float ss = a.x * a.x + a.y * a.y + a.z * a.z + a.w * a.w +
               b.x * b.x + b.y * b.y + b.z * b.z + b.w * b.w;
#pragma unroll
    for (int off = 1; off < 64; off <<= 1) {
        s  += __shfl_xor(s, off);
        ss += __shfl_xor(ss, off);
    }
    float mean = s * (1.f / 512.f);
    float var  = ss * (1.f / 512.f) - mean * mean;
    float rstd = rsqrtf(fmaxf(var, 0.f) + 1e-5f);
    const float4* gr = (const float4*)gam + lane * 2;
    const float4* br = (const float4*)bet + lane * 2;
    float4 g0 = gr[0], g1 = gr[1], b0 = br[0], b1 = br[1];
    bf16x8 hv;
    hv[0] = (bf16)((a.x - mean) * rstd * g0.x + b0.x);
    hv[1] = (bf16)((a.y - mean) * rstd * g0.y + b0.y);
    hv[2] = (bf16)((a.z - mean) * rstd * g0.z + b0.z);
    hv[3] = (bf16)((a.w - mean) * rstd * g0.w + b0.w);
    hv[4] = (bf16)((b.x - mean) * rstd * g1.x + b1.x);
    hv[5] = (bf16)((b.y - mean) * rstd * g1.y + b1.y);
    hv[6] = (bf16)((b.z - mean) * rstd * g1.z + b1.z);
    hv[7] = (bf16)((b.w - mean) * rstd * g1.w + b1.w);
    *(bf16x8*)(h + (size_t)row * 512 + lane * 8) = hv;
}

// ------- fused residual + LayerNorm: x_out = x_in + t ; h = LN(x_out) ------
__global__ __launch_bounds__(256) void resln_kernel(const bf16* __restrict__ t,
                                                    const float* __restrict__ xin,
                                                    float* __restrict__ xout,
                                                    const float* __restrict__ gam,
                                                    const float* __restrict__ bet,
                                                    bf16* __restrict__ h) {
    int row  = blockIdx.x * 4 + (threadIdx.x >> 6);
    int lane = threadIdx.x & 63;
    const float4* xr = (const float4*)(xin + (size_t)row * 512) + lane * 2;
    float4 a = xr[0], b = xr[1];
    bf16x8 tv = *(const bf16x8*)(t + (size_t)row * 512 + lane * 8);
    a.x += (float)tv[0]; a.y += (float)tv[1]; a.z += (float)tv[2]; a.w += (float)tv[3];
    b.x += (float)tv[4]; b.y += (float)tv[5]; b.z += (float)tv[6]; b.w += (float)tv[7];
    float4* xw = (float4*)(xout + (size_t)row * 512) + lane * 2;
    xw[0] = a; xw[1] = b;
    float s  = a.x + a.y + a.z + a.w + b.x + b.y + b.z + b.w;
    float ss = a.x * a.x + a.y * a.y + a.z * a.z + a.w * a.w +
               b.x * b.x + b.y * b.y + b.z * b.z + b.w * b.w;
#pragma unroll
    for (int off = 1; off < 64; off <<= 1) {
        s  += __shfl_xor(s, off);
        ss += __shfl_xor(ss, off);
    }
    float mean = s * (1.f / 512.f);
    float var  = ss * (1.f / 512.f) - mean * mean;
    float rstd = rsqrtf(fmaxf(var, 0.f) + 1e-5f);
    const float4* gr = (const float4*)gam + lane * 2;
    const float4* br = (const float4*)bet + lane * 2;
    float4 g0 = gr[0], g1 = gr[1], b0 = br[0], b1 = br[1];
    bf16x8 hv;
    hv[0] = (bf16)((a.x - mean) * rstd * g0.x + b0.x);
    hv[1] = (bf16)((a.y - mean) * rstd * g0.y + b0.y);
    hv[2] = (bf16)((a.z - mean) * rstd * g0.z + b0.z);
    hv[3] = (bf16)((a.w - mean) * rstd * g0.w + b0.w);
    hv[4] = (bf16)((b.x - mean) * rstd * g1.x + b1.x);
    hv[5] = (bf16)((b.y - mean) * rstd * g1.y + b1.y);
    hv[6] = (bf16)((b.z - mean) * rstd * g1.z + b1.z);
    hv[7] = (bf16)((b.w - mean) * rstd * g1.w + b1.w);
    *(bf16x8*)(h + (size_t)row * 512 + lane * 8) = hv;
}

// ------------- transpose+convert: in f32 [L][K][N] -> out bf16 [L][N][K] ---
__global__ void wtrans_kernel(const float* __restrict__ in, bf16* __restrict__ out,
                              int K, int N) {
    __shared__ float tile[32][33];
    int n0 = blockIdx.x * 32, k0 = blockIdx.y * 32;
    const float* ip = in + (size_t)blockIdx.z * K * N;
    bf16* op = out + (size_t)blockIdx.z * N * K;
#pragma unroll
    for (int i = threadIdx.y; i < 32; i += 8)
        tile[i][threadIdx.x] = ip[(size_t)(k0 + i) * N + n0 + threadIdx.x];
    __syncthreads();
#pragma unroll
    for (int i = threadIdx.y; i < 32; i += 8)
        op[(size_t)(n0 + i) * K + k0 + threadIdx.x] = (bf16)tile[threadIdx.x][i];
}

// ------------- elementwise f32 -> bf16 ------------------------------------
__global__ void cvt_kernel(const float* __restrict__ in, bf16* __restrict__ out, int n) {
    int i = (blockIdx.x * 256 + threadIdx.x) * 8;
    if (i + 8 <= n) {
        const float4* p = (const float4*)(in + i);
        float4 a = p[0], b = p[1];
        bf16x8 v;
        v[0] = (bf16)a.x; v[1] = (bf16)a.y; v[2] = (bf16)a.z; v[3] = (bf16)a.w;
        v[4] = (bf16)b.x; v[5] = (bf16)b.y; v[6] = (bf16)b.z; v[7] = (bf16)b.w;
        *(bf16x8*)(out + i) = v;
    }
}

// ------------- V transpose (self): qkvb V-slice -> VT[bh][64][T] bf16 ------
__global__ __launch_bounds__(256) void vtrans_self(const bf16* __restrict__ qkvb,
                                                   bf16* __restrict__ VTs, int T_) {
    __shared__ bf16 tl[64][66];
    int tb = blockIdx.x * 64;
    int bh = blockIdx.y;
    int b = bh >> 3, h = bh & 7;
    int tid = threadIdx.x;
#pragma unroll
    for (int e = 0; e < 2; ++e) {
        int idx = e * 256 + tid;         // 0..511: t x 8ch-groups
        int t = idx >> 3, ci = (idx & 7) * 8;
        bf16x8 v = *(const bf16x8*)(qkvb + ((size_t)b * T_ + tb + t) * 1536 +
                                    h * 192 + 128 + ci);
#pragma unroll
        for (int j = 0; j < 8; ++j) tl[ci + j][t] = v[j];
    }
    __syncthreads();
#pragma unroll
    for (int e = 0; e < 2; ++e) {
        int idx = e * 256 + tid;
        int ch = idx >> 3, ti = (idx & 7) * 8;
        bf16x8 v;
#pragma unroll
        for (int j = 0; j < 8; ++j) v[j] = tl[ch][ti + j];
        *(bf16x8*)(VTs + ((size_t)bh * 64 + ch) * T_ + tb + ti) = v;
    }
}

// ------------- V transpose (cross): cond_v f32 -> VT[bh][64][S] bf16 -------
__global__ __launch_bounds__(256) void vtrans_cross(const float* __restrict__ cv,
                                                    bf16* __restrict__ VTc, int S_) {
    __shared__ bf16 tl[64][66];
    int sb = blockIdx.x * 64;
    int bh = blockIdx.y;
    int b = bh >> 3, h = bh & 7;
    int tid = threadIdx.x;
#pragma unroll
    for (int e = 0; e < 4; ++e) {
        int idx = e * 256 + tid;         // 0..1023: s x 16 ch-groups(4)
        int s = idx >> 4, ci = (idx & 15) * 4;
        float4 v = *(const float4*)(cv + ((size_t)b * S_ + sb + s) * 512 + h * 64 + ci);
        tl[ci + 0][s] = (bf16)v.x; tl[ci + 1][s] = (bf16)v.y;
        tl[ci + 2][s] = (bf16)v.z; tl[ci + 3][s] = (bf16)v.w;
    }
    __syncthreads();
#pragma unroll
    for (int e = 0; e < 2; ++e) {
        int idx = e * 256 + tid;
        int ch = idx >> 3, si = (idx & 7) * 8;
        bf16x8 v;
#pragma unroll
        for (int j = 0; j < 8; ++j) v[j] = tl[ch][si + j];
        *(bf16x8*)(VTc + ((size_t)bh * 64 + ch) * S_ + sb + si) = v;
    }
}

// ------------- GEMM: C = A[M][K] @ Bt[N][K]^T + bias, BM x BN tile ---------
// Depth-2 counted-vmcnt pipeline (R9, proven). 4 waves in 2x2 layout.
template <int EPI, int BM, int BN>
__global__ __launch_bounds__(256) void gemm_kernel(const bf16* __restrict__ A,
                                                   const bf16* __restrict__ Bt,
                                                   const float* __restrict__ bias,
                                                   const float* res, void* out,
                                                   int M, int N, int K) {
    constexpr int MI = BM / 32;          // row frags per wave
    constexpr int NI = BN / 32;          // col frags per wave
    constexpr int LPW = BM / 32 + BN / 32;  // vmem insts per thread per stage
    constexpr int ABYTES = BM * 128;     // bytes per A buffer
    constexpr int BBYTES = BN * 128;     // bytes per B buffer
    __shared__ __align__(16) bf16 As[2 * BM * 64];
    __shared__ __align__(16) bf16 Bs[2 * BN * 64];
    int tiles_n = N / BN;
    int bid = blockIdx.x;
    int cpx = gridDim.x >> 3;           // grid % 8 == 0 for all our launches
    bid = (bid & 7) * cpx + (bid >> 3); // XCD-aware swizzle
    int bm = bid / tiles_n, bn = bid % tiles_n;
    int tid = threadIdx.x, wave = tid >> 6, lane = tid & 63;
    int wm = wave >> 1, wn = wave & 1;
    int g = lane >> 4, cc = lane & 15;
    f32x4 acc[MI][NI] = {};
    const bf16* Ag = A + (size_t)(bm * BM) * K;
    const bf16* Bg = Bt + (size_t)(bn * BN) * K;
    int scol = (tid & 7) * 8;  // element offset within 64-wide row

    auto stage = [&](int k0, int buf) {
#pragma unroll
        for (int e = 0; e < BM / 32; ++e) {
            int row = (e * 256 + tid) >> 3;
            __builtin_amdgcn_global_load_lds(AS1(Ag + (size_t)row * K + k0 + scol),
                                             AS3((char*)As + buf * ABYTES + e * 4096 + wave * 1024),
                                             16, 0, 0);
        }
#pragma unroll
        for (int e = 0; e < BN / 32; ++e) {
            int row = (e * 256 + tid) >> 3;
            __builtin_amdgcn_global_load_lds(AS1(Bg + (size_t)row * K + k0 + scol),
                                             AS3((char*)Bs + buf * BBYTES + e * 4096 + wave * 1024),
                                             16, 0, 0);
        }
    };

    int nk = K >> 6;                     // >= 8 for all our shapes
    stage(0, 0);
    stage(64, 1);
    for (int t = 0; t < nk; ++t) {
        if (t + 1 < nk) vmbar<LPW>(); else vmbar<0>();
        const bf16* Ab = As + (t & 1) * (BM * 64);
        const bf16* Bb = Bs + (t & 1) * (BN * 64);
#pragma unroll
        for (int kk = 0; kk < 2; ++kk) {
            bf16x8 af[MI], bfr[NI];
#pragma unroll
            for (int mi = 0; mi < MI; ++mi)
                af[mi] = *(const bf16x8*)(Ab + (wm * (BM / 2) + mi * 16 + cc) * 64 + kk * 32 + g * 8);
#pragma unroll
            for (int ni = 0; ni < NI; ++ni)
                bfr[ni] = *(const bf16x8*)(Bb + (wn * (BN / 2) + ni * 16 + cc) * 64 + kk * 32 + g * 8);
#pragma unroll
            for (int mi = 0; mi < MI; ++mi)
#pragma unroll
                for (int ni = 0; ni < NI; ++ni)
                    acc[mi][ni] = __builtin_amdgcn_mfma_f32_16x16x32_bf16(
                        af[mi], bfr[ni], acc[mi][ni], 0, 0, 0);
        }
        plainbar();                       // everyone done reading buf[t&1]
        if (t + 2 < nk) stage((t + 2) * 64, t & 1);
    }
    // epilogue: D[m = 4*(lane>>4)+r][n = lane&15] per 16x16 fragment
    int m0 = bm * BM + wm * (BM / 2);
    int n0 = bn * BN + wn * (BN / 2);
#pragma unroll
    for (int ni = 0; ni < NI; ++ni) {
        int n = n0 + ni * 16 + cc;
        float bv = bias[n];
#pragma unroll
        for (int mi = 0; mi < MI; ++mi) {
#pragma unroll
            for (int r = 0; r < 4; ++r) {
                int m = m0 + mi * 16 + g * 4 + r;
                float v = acc[mi][ni][r] + bv;
                if (EPI == 1) v = 0.5f * v * (1.f + erff(v * 0.70710678118654752f));
                if (EPI == 2)
                    ((float*)out)[(size_t)m * N + n] = res[(size_t)m * N + n] + v;
                else
                    ((bf16*)out)[(size_t)m * N + n] = (bf16)v;
            }
        }
    }
}

// ------------- flash attention v10: intra-wave pipelined tile --------------
// R12 structure (64 q, 8 waves, KVBLK=128, 1 barrier/tile) with the tile
// body software-pipelined: vf reads issued right after QK^T (latency hides
// under softmax); pa[0] read issued after the first softmax half; PV runs
// on pre-loaded registers. No sync-structure change.
__global__ __launch_bounds__(512) void attn_kernel(
    const bf16* __restrict__ Qp, int q_rs, int q_hs,
    const bf16* __restrict__ Kp, int k_rs, int k_hs,
    const bf16* __restrict__ Vt, int vt_s,
    bf16* __restrict__ Op, int T_, int S_) {
    __shared__ __align__(16) char SM[81920];
    // [0,32768): K dbuf 2 x [128 s][64 ch], 128B rows, chunk^(row&7)
    // [32768,65536): V^T dbuf 2 x [64 ch][128 s], 256B rows, chunk^(row&15)
    // [65536,81920): P, 8 waves x 2KB ([16 q][64 s], 128B rows, chunk^(cc&7))

    int numQ = T_ >> 6;
    int phys = blockIdx.x;
    int cpx = gridDim.x >> 3;              // grid % 8 == 0
    int bid = (phys & 7) * cpx + (phys >> 3);
    int qb = bid % numQ;
    int bh = bid / numQ;
    int b = bh >> 3, h = bh & 7;
    int tid = threadIdx.x, wave = tid >> 6, lane = tid & 63;
    int wq = wave >> 1, ws = wave & 1;     // q-block, s-half
    int g = lane >> 4, cc = lane & 15;
    int qrow0 = qb * 64;
    int swz = cc & 7;

    const bf16* Qb = Qp + ((size_t)b * T_ + qrow0 + wq * 16) * q_rs + h * q_hs;
    const bf16* Kb = Kp + ((size_t)b * S_) * k_rs + h * k_hs;
    const bf16* Vtb = Vt + (size_t)bh * 64 * vt_s;

    // Q fragments (B-operand): lane holds Q[q=wq*16+cc][k=kk*32+8g+j],
    // pre-scaled by (1/sqrt(ch))*log2(e) so softmax is exp2() directly.
    const float QSC = 0.125f * 1.44269504088896f;
    bf16x8 qf[2];
#pragma unroll
    for (int kk = 0; kk < 2; ++kk) {
        bf16x8 raw = *(const bf16x8*)(Qb + (size_t)cc * q_rs + kk * 32 + g * 8);
        bf16x8 sc;
#pragma unroll
        for (int j = 0; j < 8; ++j) sc[j] = (bf16)((float)raw[j] * QSC);
        qf[kk] = sc;
    }

    float l_acc = 0.f;
    f32x4 o_acc[4] = {};
    char* Pw = SM + 65536 + wave * 2048;

    auto stage = [&](int s0, int buf) {
        // K tile 128x64: 2 x 16B per thread; source pre-swizzled.
#pragma unroll
        for (int e = 0; e < 2; ++e) {
            int L = e * 512 + tid;
            int row = L >> 3, cp = L & 7;
            int col = (cp ^ (row & 7)) * 8;
            __builtin_amdgcn_global_load_lds(AS1(Kb + (size_t)(s0 + row) * k_rs + col),
                                             AS3(SM + buf * 16384 + e * 8192 + wave * 1024), 16, 0, 0);
        }
        // V^T tile 64x128 (256B rows): 2 x 16B per thread; source pre-swizzled.
#pragma unroll
        for (int e = 0; e < 2; ++e) {
            int L = e * 512 + tid;
            int row = L >> 4, cp = L & 15;
            int scl = (cp ^ (row & 15)) * 8;
            __builtin_amdgcn_global_load_lds(AS1(Vtb + (size_t)row * vt_s + s0 + scl),
                                             AS3(SM + 32768 + buf * 16384 + e * 8192 + wave * 1024), 16, 0, 0);
        }
    };

    stage(0, 0);
    __syncthreads();

    int nt = S_ >> 7;
    int cur = 0;
    for (int t = 0; t < nt; ++t) {
        if (t + 1 < nt) stage((t + 1) * 128, cur ^ 1);
        char* kbc = SM + cur * 16384;
        char* vbc = SM + 32768 + cur * 16384;
        // ---- QK^T (swapped): sf[sn][r] = S^T[s=ws*64+sn*16+4g+r][q=wq*16+cc]
        f32x4 sf[4] = {};
        __builtin_amdgcn_s_setprio(1);
#pragma unroll
        for (int kk = 0; kk < 2; ++kk)
#pragma unroll
            for (int sn = 0; sn < 4; ++sn) {
                int row = ws * 64 + sn * 16 + cc;
                bf16x8 kf = *(const bf16x8*)(kbc + row * 128 + (((kk * 4 + g) ^ (row & 7)) << 4));
                sf[sn] = __builtin_amdgcn_mfma_f32_16x16x32_bf16(kf, qf[kk], sf[sn], 0, 0, 0);
            }
        __builtin_amdgcn_s_setprio(0);
        // ---- prefetch ALL vf fragments now (dep only on V buffer);
        //      latency hides under the softmax VALU chain below.
        bf16x8 vf[2][4];
#pragma unroll
        for (int kk = 0; kk < 2; ++kk)
#pragma unroll
            for (int ni = 0; ni < 4; ++ni) {
                int vrow = ni * 16 + cc;
                vf[kk][ni] = *(const bf16x8*)(vbc + vrow * 256 +
                                              (((ws * 8 + kk * 4 + g) ^ (vrow & 15)) << 4));
            }
        // ---- softmax half 1 (sn 0,1 -> P chunks 0..3), then pa0 read ----
        bf16x8 pa0, pa1;
#pragma unroll
        for (int sn = 0; sn < 2; ++sn) {
            float p0 = exp2f(sf[sn][0]), p1 = exp2f(sf[sn][1]);
            float p2 = exp2f(sf[sn][2]), p3 = exp2f(sf[sn][3]);
            l_acc += (p0 + p1) + (p2 + p3);
            uint32_t u01, u23;
            asm("v_cvt_pk_bf16_f32 %0, %1, %2" : "=v"(u01) : "v"(p0), "v"(p1));
            asm("v_cvt_pk_bf16_f32 %0, %1, %2" : "=v"(u23) : "v"(p2), "v"(p3));
            char* pb = Pw + cc * 128 + (((sn * 2 + (g >> 1)) ^ swz) << 4) + (g & 1) * 8;
            uint2 uu; uu.x = u01; uu.y = u23;
            *(uint2*)pb = uu;
        }
        pa0 = *(const bf16x8*)(Pw + cc * 128 + (((0 * 4 + g) ^ swz) << 4));
        // ---- softmax half 2 (sn 2,3 -> P chunks 4..7), then pa1 read ----
#pragma unroll
        for (int sn = 2; sn < 4; ++sn) {
            float p0 = exp2f(sf[sn][0]), p1 = exp2f(sf[sn][1]);
            float p2 = exp2f(sf[sn][2]), p3 = exp2f(sf[sn][3]);
            l_acc += (p0 + p1) + (p2 + p3);
            uint32_t u01, u23;
            asm("v_cvt_pk_bf16_f32 %0, %1, %2" : "=v"(u01) : "v"(p0), "v"(p1));
            asm("v_cvt_pk_bf16_f32 %0, %1, %2" : "=v"(u23) : "v"(p2), "v"(p3));
            char* pb = Pw + cc * 128 + (((sn * 2 + (g >> 1)) ^ swz) << 4) + (g & 1) * 8;
            uint2 uu; uu.x = u01; uu.y = u23;
            *(uint2*)pb = uu;
        }
        pa1 = *(const bf16x8*)(Pw + cc * 128 + (((1 * 4 + g) ^ swz) << 4));
        // ---- PV on pre-loaded registers ----
        __builtin_amdgcn_s_setprio(1);
#pragma unroll
        for (int ni = 0; ni < 4; ++ni)
            o_acc[ni] = __builtin_amdgcn_mfma_f32_16x16x32_bf16(pa0, vf[0][ni], o_acc[ni], 0, 0, 0);
#pragma unroll
        for (int ni = 0; ni < 4; ++ni)
            o_acc[ni] = __builtin_amdgcn_mfma_f32_16x16x32_bf16(pa1, vf[1][ni], o_acc[ni], 0, 0, 0);
        __builtin_amdgcn_s_setprio(0);
        __syncthreads();  // ONE barrier per 128-tile: release bufs + drain stage
        cur ^= 1;
    }

    // ---- cross-half combine (ws partials -> full), in LDS ----
    l_acc += __shfl_xor(l_acc, 16);
    l_acc += __shfl_xor(l_acc, 32);   // lane (g,cc): full half-sum for q=wq*16+cc
    float* sco = (float*)SM;          // 8 waves x [16 q][64 ch] f32 = 32KB
    float* lf = (float*)(SM + 65536); // 8 waves x 16 q (over dead P)
    float* scw = sco + wave * 1024;
#pragma unroll
    for (int ni = 0; ni < 4; ++ni)
#pragma unroll
        for (int r = 0; r < 4; ++r)
            scw[(4 * g + r) * 64 + ni * 16 + cc] = o_acc[ni][r];
    if (g == 0) lf[wave * 16 + cc] = l_acc;
    __syncthreads();
    int q = tid >> 3, c0 = (tid & 7) * 8;   // q 0..63, ch base 0..56
    int wqq = q >> 4, qr = q & 15;
    float l = lf[(wqq * 2) * 16 + qr] + lf[(wqq * 2 + 1) * 16 + qr];
    float inv = 1.f / l;
    const float* p0p = sco + (wqq * 2) * 1024 + qr * 64 + c0;
    const float* p1p = sco + (wqq * 2 + 1) * 1024 + qr * 64 + c0;
    bf16x8 o1;
#pragma unroll
    for (int e = 0; e < 2; ++e) {
        float4 v0 = *(const float4*)(p0p + e * 4);
        float4 v1 = *(const float4*)(p1p + e * 4);
        o1[e * 4 + 0] = (bf16)((v0.x + v1.x) * inv);
        o1[e * 4 + 1] = (bf16)((v0.y + v1.y) * inv);
        o1[e * 4 + 2] = (bf16)((v0.z + v1.z) * inv);
        o1[e * 4 + 3] = (bf16)((v0.w + v1.w) * inv);
    }
    *(bf16x8*)(Op + ((size_t)b * T_ + qrow0 + q) * 512 + h * 64 + c0) = o1;
}

// ---------------------------------------------------------------------------
extern "C" void kernel_launch(void* const* d_in, const int* in_sizes, int n_in,
                              void* d_out, int out_size, void* d_ws, size_t ws_size,
                              hipStream_t stream) {
    const float* x_in    = (const float*)d_in[0];
    const float* cond_k  = (const float*)d_in[1];
    const float* cond_v  = (const float*)d_in[2];
    const float* qkv_w   = (const float*)d_in[3];
    const float* qkv_b   = (const float*)d_in[4];
    const float* attn_w  = (const float*)d_in[5];
    const float* attn_b  = (const float*)d_in[6];
    const float* cross_w = (const float*)d_in[7];
    const float* cross_b = (const float*)d_in[8];
    const float* fc_w    = (const float*)d_in[9];
    const float* fc_b    = (const float*)d_in[10];
    const float* mlp_w   = (const float*)d_in[11];
    const float* mlp_b   = (const float*)d_in[12];
    const float* ln1_g   = (const float*)d_in[13];
    const float* ln1_b   = (const float*)d_in[14];
    const float* ln3_g   = (const float*)d_in[15];
    const float* ln3_b   = (const float*)d_in[16];
    const float* ln4_g   = (const float*)d_in[17];
    const float* ln4_b   = (const float*)d_in[18];

    const int L = 4, T = 2048, S = 512, W = 512;
    const int M = 2 * T;  // B*T rows

    char* ws = (char*)d_ws;
    size_t off = 0;
    auto carve = [&](size_t bytes) -> char* {
        char* p = ws + off;
        off += (bytes + 255) & ~(size_t)255;
        return p;
    };
    bf16* wqkv  = (bf16*)carve((size_t)L * 1536 * 512 * 2);
    bf16* wattn = (bf16*)carve((size_t)L * 512 * 512 * 2);
    bf16* wcrs  = (bf16*)carve((size_t)L * 512 * 512 * 2);
    bf16* wfc   = (bf16*)carve((size_t)L * 2048 * 512 * 2);
    bf16* wmlp  = (bf16*)carve((size_t)L * 512 * 2048 * 2);
    bf16* ckb   = (bf16*)carve((size_t)2 * S * W * 2);
    bf16* VTs   = (bf16*)carve((size_t)16 * 64 * T * 2);   // self V^T per layer
    bf16* VTc   = (bf16*)carve((size_t)16 * 64 * S * 2);   // cross V^T (once)
    bf16* hbuf  = (bf16*)carve((size_t)M * 512 * 2);
    bf16* qkvb  = (bf16*)carve((size_t)M * 1536 * 2);
    bf16* abuf  = (bf16*)carve((size_t)M * 512 * 2);
    bf16* fcb   = (bf16*)carve((size_t)M * 2048 * 2);
    bf16* tbuf  = qkvb;  // proj outputs reuse qkvb (dead after attn)

    dim3 tb(32, 8);
    wtrans_kernel<<<dim3(1536 / 32, 512 / 32, L), tb, 0, stream>>>(qkv_w, wqkv, 512, 1536);
    wtrans_kernel<<<dim3(512 / 32, 512 / 32, L), tb, 0, stream>>>(attn_w, wattn, 512, 512);
    wtrans_kernel<<<dim3(512 / 32, 512 / 32, L), tb, 0, stream>>>(cross_w, wcrs, 512, 512);
    wtrans_kernel<<<dim3(2048 / 32, 512 / 32, L), tb, 0, stream>>>(fc_w, wfc, 512, 2048);
    wtrans_kernel<<<dim3(512 / 32, 2048 / 32, L), tb, 0, stream>>>(mlp_w, wmlp, 2048, 512);
    cvt_kernel<<<(2 * S * W) / 2048, 256, 0, stream>>>(cond_k, ckb, 2 * S * W);
    vtrans_cross<<<dim3(S / 64, 16), 256, 0, stream>>>(cond_v, VTc, S);

    float* x = (float*)d_out;   // first written by layer-0 attn-proj resln

    const int nAttn = 16 * (T / 64);        // 512 blocks
    for (int i = 0; i < L; ++i) {
        // ---- self-attention sub-block ----
        if (i == 0)   // later layers: hbuf produced by previous mlp resln
            ln_kernel<<<M / 4, 256, 0, stream>>>(x_in, ln1_g, ln1_b, hbuf);
        gemm_kernel<0, 64, 128><<<(M / 64) * (1536 / 128), 256, 0, stream>>>(
            hbuf, wqkv + (size_t)i * 1536 * 512, qkv_b + i * 1536, nullptr, qkvb,
            M, 1536, 512);
        vtrans_self<<<dim3(T / 64, 16), 256, 0, stream>>>(qkvb, VTs, T);
        attn_kernel<<<nAttn, 512, 0, stream>>>(
            qkvb, 1536, 192, qkvb + 64, 1536, 192, VTs, T,
            abuf, T, T);
        gemm_kernel<0, 32, 64><<<(M / 32) * (512 / 64), 256, 0, stream>>>(
            abuf, wattn + (size_t)i * 512 * 512, attn_b + i * 512, nullptr, tbuf,
            M, 512, 512);
        resln_kernel<<<M / 4, 256, 0, stream>>>(
            tbuf, (i == 0) ? x_in : x, x, ln3_g + i * 512, ln3_b + i * 512, hbuf);
        // ---- cross-attention sub-block ----
        attn_kernel<<<nAttn, 512, 0, stream>>>(
            hbuf, 512, 64, ckb, 512, 64, VTc, S,
            abuf, T, S);
        gemm_kernel<0, 32, 64><<<(M / 32) * (512 / 64), 256, 0, stream>>>(
            abuf, wcrs + (size_t)i * 512 * 512, cross_b + i * 512, nullptr, tbuf,
            M, 512, 512);
        resln_kernel<<<M / 4, 256, 0, stream>>>(
            tbuf, x, x, ln4_g + i * 512, ln4_b + i * 512, hbuf);
        // ---- MLP sub-block ----
        gemm_kernel<1, 128, 128><<<(M / 128) * (2048 / 128), 256, 0, stream>>>(
            hbuf, wfc + (size_t)i * 2048 * 512, fc_b + i * 2048, nullptr, fcb,
            M, 2048, 512);
        if (i + 1 < L) {
            gemm_kernel<0, 32, 64><<<(M / 32) * (512 / 64), 256, 0, stream>>>(
                fcb, wmlp + (size_t)i * 512 * 2048, mlp_b + i * 512, nullptr, tbuf,
                M, 512, 2048);
            resln_kernel<<<M / 4, 256, 0, stream>>>(
                tbuf, x, x, ln1_g + (i + 1) * 512, ln1_b + (i + 1) * 512, hbuf);
        } else {
            gemm_kernel<2, 32, 64><<<(M / 32) * (512 / 64), 256, 0, stream>>>(
                fcb, wmlp + (size_t)i * 512 * 2048, mlp_b + i * 512, x, x,
                M, 512, 2048);
        }
    }
}